// Round 16
// baseline (271.983 us; speedup 1.0000x reference)
//
#include <hip/hip_runtime.h>
#include <math.h>

#define B_ 16
#define T_ 2048
#define D_ 512
#define DB_ 128
#define K_ 7
#define TOPK_ 16
#define WIN_ 64

static constexpr float SCALE_ = 0.08838834764831845f;   // 128^-0.5
static constexpr float PHI_ = 1.618033988749895f;
static constexpr float PSI_ = -0.6180339887498949f;
static constexpr float INV_DENOM_ = 0.4472135954999579f; // 1/(PHI-PSI)
static constexpr float NEGV = -1e30f;
static constexpr float NEGINF = -3.402823466e38f;
#define IMAXI 0x7FFFFFFF

typedef __attribute__((ext_vector_type(8))) __bf16 bf16x8;
typedef __attribute__((ext_vector_type(8))) unsigned short u16x8;
typedef __attribute__((ext_vector_type(4))) float f32x4;

__device__ inline float softplusf(float x){
    return fmaxf(x, 0.f) + log1pf(expf(-fabsf(x)));
}
__device__ inline unsigned short f2bf(float x){
    unsigned int u = __float_as_uint(x);
    unsigned int r = (u + 0x7FFFu + ((u >> 16) & 1u)) >> 16;
    return (unsigned short)r;
}
__device__ inline float bf2f(unsigned short h){
    return __uint_as_float(((unsigned int)h) << 16);
}
__device__ inline bf16x8 ld_bf8(const unsigned short* p){
    u16x8 r = *(const u16x8*)p;
    return __builtin_bit_cast(bf16x8, r);
}
__device__ inline unsigned int pkbf(float a, float b){
    unsigned int r;
    asm("v_cvt_pk_bf16_f32 %0, %1, %2" : "=v"(r) : "v"(a), "v"(b));
    return r;
}
typedef __attribute__((address_space(3))) unsigned int as3_u32;
typedef const __attribute__((address_space(1))) unsigned int as1_u32c;
__device__ inline void gload16(const void* g, void* l){
    __builtin_amdgcn_global_load_lds((as1_u32c*)g, (as3_u32*)l, 16, 0, 0);
}

// ---------------- prep: LN(X_write)->Xh/Xl (wave-per-row) | W0->hi/lo | qmean partials -----
__global__ __launch_bounds__(256) void prep_kernel(const float* __restrict__ X,
                                                   const float* __restrict__ w,
                                                   const float* __restrict__ b,
                                                   unsigned short* __restrict__ Xh,
                                                   unsigned short* __restrict__ Xl,
                                                   const float* __restrict__ W0,
                                                   unsigned short* __restrict__ Wh,
                                                   unsigned short* __restrict__ Wl,
                                                   const float* __restrict__ Xr,
                                                   float* __restrict__ qpart)
{
    int bx = blockIdx.x;
    int tid = threadIdx.x;
    if (bx < 4096) {
        int lane = tid & 63, wv = tid >> 6;
        int row = bx * 8 + wv * 2;
        float4 wv0 = *(const float4*)(w + lane*4);
        float4 wv1 = *(const float4*)(w + 256 + lane*4);
        float4 bv0 = *(const float4*)(b + lane*4);
        float4 bv1 = *(const float4*)(b + 256 + lane*4);
        #pragma unroll
        for (int rr = 0; rr < 2; rr++) {
            const float* x = X + (size_t)(row + rr) * D_;
            float4 v0 = *(const float4*)(x + lane*4);
            float4 v1 = *(const float4*)(x + 256 + lane*4);
            float s  = v0.x+v0.y+v0.z+v0.w + v1.x+v1.y+v1.z+v1.w;
            float ss = v0.x*v0.x+v0.y*v0.y+v0.z*v0.z+v0.w*v0.w
                     + v1.x*v1.x+v1.y*v1.y+v1.z*v1.z+v1.w*v1.w;
            #pragma unroll
            for (int off = 32; off; off >>= 1) { s += __shfl_xor(s, off); ss += __shfl_xor(ss, off); }
            float mu = s * (1.f/512.f);
            float rs = rsqrtf(ss*(1.f/512.f) - mu*mu + 1e-5f);
            float o0 = (v0.x - mu)*rs*wv0.x + bv0.x;
            float o1 = (v0.y - mu)*rs*wv0.y + bv0.y;
            float o2 = (v0.z - mu)*rs*wv0.z + bv0.z;
            float o3 = (v0.w - mu)*rs*wv0.w + bv0.w;
            float o4 = (v1.x - mu)*rs*wv1.x + bv1.x;
            float o5 = (v1.y - mu)*rs*wv1.y + bv1.y;
            float o6 = (v1.z - mu)*rs*wv1.z + bv1.z;
            float o7 = (v1.w - mu)*rs*wv1.w + bv1.w;
            unsigned short h0 = f2bf(o0), h1 = f2bf(o1), h2 = f2bf(o2), h3 = f2bf(o3);
            unsigned short h4 = f2bf(o4), h5 = f2bf(o5), h6 = f2bf(o6), h7 = f2bf(o7);
            uint2 hA; hA.x = (unsigned int)h0 | ((unsigned int)h1 << 16);
                      hA.y = (unsigned int)h2 | ((unsigned int)h3 << 16);
            uint2 hB; hB.x = (unsigned int)h4 | ((unsigned int)h5 << 16);
                      hB.y = (unsigned int)h6 | ((unsigned int)h7 << 16);
            uint2 lA; lA.x = (unsigned int)f2bf(o0 - bf2f(h0)) | ((unsigned int)f2bf(o1 - bf2f(h1)) << 16);
                      lA.y = (unsigned int)f2bf(o2 - bf2f(h2)) | ((unsigned int)f2bf(o3 - bf2f(h3)) << 16);
            uint2 lB; lB.x = (unsigned int)f2bf(o4 - bf2f(h4)) | ((unsigned int)f2bf(o5 - bf2f(h5)) << 16);
                      lB.y = (unsigned int)f2bf(o6 - bf2f(h6)) | ((unsigned int)f2bf(o7 - bf2f(h7)) << 16);
            unsigned short* xh = Xh + (size_t)(row + rr) * D_;
            unsigned short* xl = Xl + (size_t)(row + rr) * D_;
            *(uint2*)(xh + lane*4) = hA;
            *(uint2*)(xh + 256 + lane*4) = hB;
            *(uint2*)(xl + lane*4) = lA;
            *(uint2*)(xl + 256 + lane*4) = lB;
        }
    } else if (bx < 4352) {
        int gid = (bx - 4096) * 256 + tid;
        float4 v = ((const float4*)W0)[gid];
        unsigned short h0 = f2bf(v.x), h1 = f2bf(v.y), h2 = f2bf(v.z), h3 = f2bf(v.w);
        ushort4 hv = make_ushort4(h0, h1, h2, h3);
        ushort4 lv = make_ushort4(f2bf(v.x - bf2f(h0)), f2bf(v.y - bf2f(h1)),
                                  f2bf(v.z - bf2f(h2)), f2bf(v.w - bf2f(h3)));
        *(ushort4*)&Wh[(size_t)gid*4] = hv;
        *(ushort4*)&Wl[(size_t)gid*4] = lv;
    } else {
        int idx = bx - 4352;
        int b_ = idx >> 5, c = idx & 31;
        const float* base = Xr + ((size_t)(b_*T_ + c*64)) * D_;
        float s0 = 0.f, s1 = 0.f;
        for (int t = 0; t < 64; t++) {
            s0 += base[(size_t)t*D_ + tid];
            s1 += base[(size_t)t*D_ + tid + 256];
        }
        qpart[((size_t)b_*32 + c)*D_ + tid] = s0;
        qpart[((size_t)b_*32 + c)*D_ + tid + 256] = s1;
    }
}

// ---------------- XW0: bf16x3 MFMA, 4-BUFFER 3-AHEAD gload_lds pipeline (counted vmcnt) ----
__global__ __launch_bounds__(256) void gemm_xw0_mfma(const unsigned short* __restrict__ Ah,
                                                     const unsigned short* __restrict__ Al,
                                                     const unsigned short* __restrict__ Wh,
                                                     const unsigned short* __restrict__ Wl,
                                                     float* __restrict__ Cf)
{
    // 4 buffers x (128 rows x 32 K) per array = 32KB/array, 128KB total LDS
    __shared__ __align__(16) unsigned short sAh[4*128*32], sAl[4*128*32], sBh[4*128*32], sBl[4*128*32];
    int t0 = blockIdx.x * 128, d0 = blockIdx.y * 128;
    int tid = threadIdx.x;
    int lane = tid & 63, wid = tid >> 6;
    int wr = wid >> 1, wc = wid & 1;
    int fr = lane & 15;
    int kc2 = ((((lane >> 4) + (fr >> 1)) & 3) * 8);

    f32x4 acc[4][4];
    #pragma unroll
    for (int m = 0; m < 4; m++)
        #pragma unroll
        for (int n = 0; n < 4; n++) acc[m][n] = (f32x4){0.f,0.f,0.f,0.f};

    const unsigned short* gs = (wid==0) ? Ah : (wid==1) ? Al : (wid==2) ? Wh : Wl;
    unsigned short* lsA = (wid==0) ? sAh : (wid==1) ? sAl : (wid==2) ? sBh : sBl;
    int rowoff = (wid < 2) ? t0 : d0;
    int cch = ((lane & 3) - ((lane >> 3) & 3)) & 3;
    const unsigned short* gbase = gs + (size_t)(rowoff + (lane >> 2))*512 + cch*8;

    // stage tile t (8 x 1KB gload_lds per wave) into buffer t&3
    auto STAGE = [&](int t){
        unsigned short* ls = lsA + (t & 3) * (128*32);
        int kk = t * 32;
        #pragma unroll
        for (int i = 0; i < 8; i++)
            gload16(gbase + (size_t)(16*i)*512 + kk, ls + i*512);
    };

    STAGE(0); STAGE(1); STAGE(2);      // 24 outstanding per wave

    for (int t = 0; t < 16; t++) {
        // wait for tile t's 8 loads (leave t+1,t+2 in flight)
        if (t <= 13)      asm volatile("s_waitcnt vmcnt(16)" ::: "memory");
        else if (t == 14) asm volatile("s_waitcnt vmcnt(8)"  ::: "memory");
        else              asm volatile("s_waitcnt vmcnt(0)"  ::: "memory");
        __builtin_amdgcn_s_barrier();  // all waves: tile t complete; tile t-1 reads done
        if (t < 13) STAGE(t + 3);      // refill freed buffer (t+3)&3 == (t-1)&3

        int bo = (t & 3) * (128*32);
        bf16x8 ahf[4], alf[4], bhf[4], blf[4];
        #pragma unroll
        for (int m = 0; m < 4; m++) {
            int r = bo + (wr*64 + m*16 + fr)*32 + kc2;
            ahf[m] = ld_bf8(&sAh[r]);
            alf[m] = ld_bf8(&sAl[r]);
        }
        #pragma unroll
        for (int n = 0; n < 4; n++) {
            int r = bo + (wc*64 + n*16 + fr)*32 + kc2;
            bhf[n] = ld_bf8(&sBh[r]);
            blf[n] = ld_bf8(&sBl[r]);
        }
        #pragma unroll
        for (int m = 0; m < 4; m++)
            #pragma unroll
            for (int n = 0; n < 4; n++) {
                acc[m][n] = __builtin_amdgcn_mfma_f32_16x16x32_bf16(bhf[n], ahf[m], acc[m][n], 0, 0, 0);
                acc[m][n] = __builtin_amdgcn_mfma_f32_16x16x32_bf16(bhf[n], alf[m], acc[m][n], 0, 0, 0);
                acc[m][n] = __builtin_amdgcn_mfma_f32_16x16x32_bf16(blf[n], ahf[m], acc[m][n], 0, 0, 0);
            }
    }

    #pragma unroll
    for (int m = 0; m < 4; m++) {
        int t = t0 + wr*64 + m*16 + fr;
        #pragma unroll
        for (int n = 0; n < 4; n++) {
            int dbase = d0 + wc*64 + n*16 + (lane >> 4)*4;
            *(f32x4*)&Cf[(size_t)t*512 + dbase] = acc[m][n];
        }
    }
}

// ---------------- sal: bf16x3 MFMA, swizzled LDS, issue-early global loads ----------------
__global__ __launch_bounds__(256) void sal_mfma(const unsigned short* __restrict__ Xh,
                                                const unsigned short* __restrict__ Xl,
                                                const float* __restrict__ Cf,
                                                float* __restrict__ sal)
{
    int b = blockIdx.x, i0 = blockIdx.y * 64;
    __shared__ __align__(16) unsigned short sAh[64*32], sAl[64*32], sBh[128*32], sBl[128*32];
    int tid = threadIdx.x;
    int lane = tid & 63, wcw = tid >> 6;
    int fr = lane & 15;
    int kc2 = ((((lane >> 4) + (fr >> 1)) & 3) * 8);

    const unsigned short* XhB = Xh + (size_t)b*T_*D_;
    const unsigned short* XlB = Xl + (size_t)b*T_*D_;
    const float* CfB = Cf + (size_t)b*T_*D_;

    f32x4 acc[4][2];
    #pragma unroll
    for (int m = 0; m < 4; m++) { acc[m][0] = (f32x4){0.f,0.f,0.f,0.f}; acc[m][1] = (f32x4){0.f,0.f,0.f,0.f}; }

    int ar = tid >> 2, ac = tid & 3;
    int aslot = (ac + (ar >> 1)) & 3;
    int brow = tid >> 1, bhh = tid & 1;
    int jrow = i0 - 64 + brow;

    uint4 rAh, rAl;
    float4 rB0[2], rB1[2];

    auto LOAD = [&](int kk){
        rAh = *(const uint4*)(XhB + (size_t)(i0 + ar)*512 + kk + ac*8);
        rAl = *(const uint4*)(XlB + (size_t)(i0 + ar)*512 + kk + ac*8);
        #pragma unroll
        for (int cc = 0; cc < 2; cc++) {
            int c = 2*bhh + cc;
            if (jrow >= 0) {
                const float* src = CfB + (size_t)jrow*512 + kk + c*8;
                rB0[cc] = *(const float4*)src;
                rB1[cc] = *(const float4*)(src + 4);
            } else {
                rB0[cc] = make_float4(0.f,0.f,0.f,0.f);
                rB1[cc] = make_float4(0.f,0.f,0.f,0.f);
            }
        }
    };
    auto WRITE = [&](){
        *(uint4*)&sAh[ar*32 + aslot*8] = rAh;
        *(uint4*)&sAl[ar*32 + aslot*8] = rAl;
        #pragma unroll
        for (int cc = 0; cc < 2; cc++) {
            int c = 2*bhh + cc;
            int slot = (c + (brow >> 1)) & 3;
            uint4 hv, lv;
            float4 v0 = rB0[cc], v1 = rB1[cc];
            unsigned int h01 = pkbf(v0.x, v0.y), h23 = pkbf(v0.z, v0.w);
            unsigned int h45 = pkbf(v1.x, v1.y), h67 = pkbf(v1.z, v1.w);
            float r0 = v0.x - __uint_as_float(h01 << 16);
            float r1 = v0.y - __uint_as_float(h01 & 0xFFFF0000u);
            float r2 = v0.z - __uint_as_float(h23 << 16);
            float r3 = v0.w - __uint_as_float(h23 & 0xFFFF0000u);
            float r4 = v1.x - __uint_as_float(h45 << 16);
            float r5 = v1.y - __uint_as_float(h45 & 0xFFFF0000u);
            float r6 = v1.z - __uint_as_float(h67 << 16);
            float r7 = v1.w - __uint_as_float(h67 & 0xFFFF0000u);
            hv.x = h01; hv.y = h23; hv.z = h45; hv.w = h67;
            lv.x = pkbf(r0, r1); lv.y = pkbf(r2, r3); lv.z = pkbf(r4, r5); lv.w = pkbf(r6, r7);
            *(uint4*)&sBh[brow*32 + slot*8] = hv;
            *(uint4*)&sBl[brow*32 + slot*8] = lv;
        }
    };

    LOAD(0);
    for (int t = 0; t < 16; t++) {
        WRITE();
        __syncthreads();
        int kkn = (t+1)*32;
        bf16x8 ahf[4], alf[4], bhf[2], blf[2];
        #pragma unroll
        for (int m = 0; m < 4; m++) {
            int r = (m*16 + fr)*32 + kc2;
            ahf[m] = ld_bf8(&sAh[r]);
            alf[m] = ld_bf8(&sAl[r]);
        }
        #pragma unroll
        for (int n = 0; n < 2; n++) {
            int r = (wcw*32 + n*16 + fr)*32 + kc2;
            bhf[n] = ld_bf8(&sBh[r]);
            blf[n] = ld_bf8(&sBl[r]);
        }
        if (t < 15) LOAD(kkn);
        #pragma unroll
        for (int m = 0; m < 4; m++)
            #pragma unroll
            for (int n = 0; n < 2; n++) {
                acc[m][n] = __builtin_amdgcn_mfma_f32_16x16x32_bf16(ahf[m], bhf[n], acc[m][n], 0, 0, 0);
                acc[m][n] = __builtin_amdgcn_mfma_f32_16x16x32_bf16(ahf[m], blf[n], acc[m][n], 0, 0, 0);
                acc[m][n] = __builtin_amdgcn_mfma_f32_16x16x32_bf16(alf[m], bhf[n], acc[m][n], 0, 0, 0);
            }
        __syncthreads();
    }

    float* salB = sal + (size_t)b*T_*WIN_;
    #pragma unroll
    for (int m = 0; m < 4; m++) {
        #pragma unroll
        for (int n = 0; n < 2; n++) {
            int jl = wcw*32 + n*16 + fr;
            #pragma unroll
            for (int r = 0; r < 4; r++) {
                int il = m*16 + (lane >> 4)*4 + r;
                int o = il - jl + 64;
                if (o >= 1 && o <= 64) {
                    int jg = i0 - 64 + jl;
                    salB[(size_t)(i0 + il)*WIN_ + (o - 1)] = (jg >= 0) ? acc[m][n][r] : NEGV;
                }
            }
        }
    }
}

// ---------------- top-16 stage 1 (y<64, static-index lists) + w0q partials (y>=64) --------
__global__ __launch_bounds__(256) void topk_stage1(const float* __restrict__ sal,
                                                   float* __restrict__ cv, int* __restrict__ ci,
                                                   const float* __restrict__ qpart,
                                                   const float* __restrict__ W0,
                                                   float* __restrict__ w0p)
{
    int b = blockIdx.x, tid = threadIdx.x;
    if (blockIdx.y >= 64) {
        int c = blockIdx.y - 64;
        __shared__ float qm[D_];
        for (int p = tid; p < D_; p += 256) {
            float s = 0.f;
            for (int cc = 0; cc < 32; cc++) s += qpart[((size_t)b*32 + cc)*D_ + p];
            qm[p] = s * (1.f/2048.f);
        }
        __syncthreads();
        int w = tid >> 6, lane = tid & 63;
        float ph = 0.f, ps = 0.f;
        for (int r = 0; r < 16; r++) {
            int d = c*64 + w*16 + r;
            const float* wr = W0 + (size_t)d*D_;
            float s = 0.f;
            #pragma unroll
            for (int q = 0; q < 8; q++) s += qm[lane + q*64] * wr[lane + q*64];
            #pragma unroll
            for (int off = 32; off; off >>= 1) s += __shfl_xor(s, off);
            float phi = (s - PSI_*qm[d]) * INV_DENOM_;
            float psi = (PHI_*qm[d] - s) * INV_DENOM_;
            ph += phi*phi; ps += psi*psi;
        }
        __shared__ float shp[4], shs[4];
        if (lane == 0) { shp[w] = ph; shs[w] = ps; }
        __syncthreads();
        if (tid == 0) {
            w0p[((size_t)b*8 + c)*2 + 0] = shp[0]+shp[1]+shp[2]+shp[3];
            w0p[((size_t)b*8 + c)*2 + 1] = shs[0]+shs[1]+shs[2]+shs[3];
        }
        return;
    }
    int c = blockIdx.y;
    const float* s = sal + (size_t)b*(T_*WIN_) + (size_t)c*2048;
    int base = c*2048;
    int lane = tid & 63, wvi = tid >> 6;
    float v0=NEGINF,v1=NEGINF,v2=NEGINF,v3=NEGINF,v4=NEGINF,v5=NEGINF,v6=NEGINF,v7=NEGINF;
    int   i0=IMAXI, i1=IMAXI, i2=IMAXI, i3=IMAXI, i4=IMAXI, i5=IMAXI, i6=IMAXI, i7=IMAXI;
    #pragma unroll
    for (int r = 0; r < 8; r++) {
        int p = tid + r*256;
        float v = s[p];
        int idx = base + p;
        if (v > v7 || (v == v7 && idx < i7)) {
            bool b6 = (v > v6) || (v == v6 && idx < i6);
            bool b5 = (v > v5) || (v == v5 && idx < i5);
            bool b4 = (v > v4) || (v == v4 && idx < i4);
            bool b3 = (v > v3) || (v == v3 && idx < i3);
            bool b2 = (v > v2) || (v == v2 && idx < i2);
            bool b1 = (v > v1) || (v == v1 && idx < i1);
            bool b0 = (v > v0) || (v == v0 && idx < i0);
            float n7 = b6 ? v6 : v;             int m7 = b6 ? i6 : idx;
            float n6 = b6 ? (b5 ? v5 : v) : v6; int m6 = b6 ? (b5 ? i5 : idx) : i6;
            float n5 = b5 ? (b4 ? v4 : v) : v5; int m5 = b5 ? (b4 ? i4 : idx) : i5;
            float n4 = b4 ? (b3 ? v3 : v) : v4; int m4 = b4 ? (b3 ? i3 : idx) : i4;
            float n3 = b3 ? (b2 ? v2 : v) : v3; int m3 = b3 ? (b2 ? i2 : idx) : i3;
            float n2 = b2 ? (b1 ? v1 : v) : v2; int m2 = b2 ? (b1 ? i1 : idx) : i2;
            float n1 = b1 ? (b0 ? v0 : v) : v1; int m1 = b1 ? (b0 ? i0 : idx) : i1;
            float n0 = b0 ? v : v0;             int m0 = b0 ? idx : i0;
            v7=n7;i7=m7; v6=n6;i6=m6; v5=n5;i5=m5; v4=n4;i4=m4;
            v3=n3;i3=m3; v2=n2;i2=m2; v1=n1;i1=m1; v0=n0;i0=m0;
        }
    }
    float* cvo = cv + (((size_t)b*64 + c)*64) + wvi*16;
    int*   cio = ci + (((size_t)b*64 + c)*64) + wvi*16;
    for (int r = 0; r < 16; r++) {
        float bv = v0; int bi = i0;
        float wv_ = bv; int wi = bi;
        #pragma unroll
        for (int off = 1; off < 64; off <<= 1) {
            float vx = __shfl_xor(wv_, off);
            int   ix = __shfl_xor(wi, off);
            if (vx > wv_ || (vx == wv_ && ix < wi)) { wv_ = vx; wi = ix; }
        }
        if (bv == wv_ && bi == wi) {
            v0=v1;i0=i1; v1=v2;i1=i2; v2=v3;i2=i3; v3=v4;i3=i4;
            v4=v5;i4=i5; v5=v6;i5=i6; v6=v7;i6=i7; v7=NEGINF;i7=IMAXI;
        }
        if (lane == 0) { cvo[r] = wv_; cio[r] = wi; }
    }
}

// ---------------- slot_head (grid B, 512thr): topk merge + alpha + y -----------------------
__global__ __launch_bounds__(512) void slot_head(
    const unsigned short* __restrict__ Xh, const unsigned short* __restrict__ Xl,
    const float* __restrict__ cv, const int* __restrict__ ci,
    float* __restrict__ yws)
{
    int b = blockIdx.x, tid = threadIdx.x;
    int lane = tid & 63, wvi = tid >> 6;      // 8 waves
    __shared__ float scv[128]; __shared__ int sci[128];
    __shared__ float tvv[16]; __shared__ int tii[16];
    __shared__ float alpha[16]; __shared__ int tis[16], tjs[16];

    const float* cvb = cv + (size_t)b*4096;
    const int*   cib = ci + (size_t)b*4096;
    float v0=NEGINF,v1=NEGINF,v2=NEGINF,v3=NEGINF,v4=NEGINF,v5=NEGINF,v6=NEGINF,v7=NEGINF;
    int   i0=IMAXI, i1=IMAXI, i2=IMAXI, i3=IMAXI, i4=IMAXI, i5=IMAXI, i6=IMAXI, i7=IMAXI;
    #pragma unroll
    for (int r = 0; r < 8; r++) {
        int p = tid + r*512;
        float v = cvb[p];
        int idx = cib[p];
        if (v > v7 || (v == v7 && idx < i7)) {
            bool b6 = (v > v6) || (v == v6 && idx < i6);
            bool b5 = (v > v5) || (v == v5 && idx < i5);
            bool b4 = (v > v4) || (v == v4 && idx < i4);
            bool b3 = (v > v3) || (v == v3 && idx < i3);
            bool b2 = (v > v2) || (v == v2 && idx < i2);
            bool b1 = (v > v1) || (v == v1 && idx < i1);
            bool b0 = (v > v0) || (v == v0 && idx < i0);
            float n7 = b6 ? v6 : v;             int m7 = b6 ? i6 : idx;
            float n6 = b6 ? (b5 ? v5 : v) : v6; int m6 = b6 ? (b5 ? i5 : idx) : i6;
            float n5 = b5 ? (b4 ? v4 : v) : v5; int m5 = b5 ? (b4 ? i4 : idx) : i5;
            float n4 = b4 ? (b3 ? v3 : v) : v4; int m4 = b4 ? (b3 ? i3 : idx) : i4;
            float n3 = b3 ? (b2 ? v2 : v) : v3; int m3 = b3 ? (b2 ? i2 : idx) : i3;
            float n2 = b2 ? (b1 ? v1 : v) : v2; int m2 = b2 ? (b1 ? i1 : idx) : i2;
            float n1 = b1 ? (b0 ? v0 : v) : v1; int m1 = b1 ? (b0 ? i0 : idx) : i1;
            float n0 = b0 ? v : v0;             int m0 = b0 ? idx : i0;
            v7=n7;i7=m7; v6=n6;i6=m6; v5=n5;i5=m5; v4=n4;i4=m4;
            v3=n3;i3=m3; v2=n2;i2=m2; v1=n1;i1=m1; v0=n0;i0=m0;
        }
    }
    for (int r = 0; r < 16; r++) {
        float bv = v0; int bi = i0;
        float wv_ = bv; int wi = bi;
        #pragma unroll
        for (int off = 1; off < 64; off <<= 1) {
            float vx = __shfl_xor(wv_, off);
            int   ix = __shfl_xor(wi, off);
            if (vx > wv_ || (vx == wv_ && ix < wi)) { wv_ = vx; wi = ix; }
        }
        if (bv == wv_ && bi == wi) {
            v0=v1;i0=i1; v1=v2;i1=i2; v2=v3;i2=i3; v3=v4;i3=i4;
            v4=v5;i4=i5; v5=v6;i5=i6; v6=v7;i6=i7; v7=NEGINF;i7=IMAXI;
        }
        if (lane == 0) { scv[wvi*16 + r] = wv_; sci[wvi*16 + r] = wi; }
    }
    __syncthreads();
    if (wvi == 0) {
        float a0 = scv[lane], a1 = scv[lane + 64];
        int   e0 = sci[lane], e1 = sci[lane + 64];
        bool sw = (a1 > a0) || (a1 == a0 && e1 < e0);
        float u0 = sw ? a1 : a0; int j0 = sw ? e1 : e0;
        float u1 = sw ? a0 : a1; int j1 = sw ? e0 : e1;
        for (int r = 0; r < 16; r++) {
            float bv = u0; int bi = j0;
            float wv_ = bv; int wi = bi;
            #pragma unroll
            for (int off = 1; off < 64; off <<= 1) {
                float vx = __shfl_xor(wv_, off);
                int   ix = __shfl_xor(wi, off);
                if (vx > wv_ || (vx == wv_ && ix < wi)) { wv_ = vx; wi = ix; }
            }
            if (bv == wv_ && bi == wi) { u0 = u1; j0 = j1; u1 = NEGINF; j1 = IMAXI; }
            if (lane == 0) { tvv[r] = wv_; tii[r] = wi; }
        }
    }
    __syncthreads();
    if (tid < 16) {
        float v = tvv[tid];
        int flat = tii[tid];
        tis[tid] = flat >> 6;
        tjs[tid] = (flat >> 6) - ((flat & 63) + 1);
        float m = v;
        #pragma unroll
        for (int off = 8; off; off >>= 1) m = fmaxf(m, __shfl_xor(m, off, 16));
        float e = expf(v - m);
        float s = e;
        #pragma unroll
        for (int off = 8; off; off >>= 1) s += __shfl_xor(s, off, 16);
        alpha[tid] = e / s;
    }
    __syncthreads();
    {
        float acc = 0.f;
        #pragma unroll
        for (int k = 0; k < 16; k++) {
            int i = tis[k], j = tjs[k];
            float xi = bf2f(Xh[((size_t)b*T_ + i)*D_ + tid]) + bf2f(Xl[((size_t)b*T_ + i)*D_ + tid]);
            float xj = bf2f(Xh[((size_t)b*T_ + j)*D_ + tid]) + bf2f(Xl[((size_t)b*T_ + j)*D_ + tid]);
            acc += alpha[k] * (xi - xj);
        }
        yws[(size_t)b*D_ + tid] = acc;
    }
}

// ---------------- slot_rt (grid (B,8)): Rt partials over 64-row W_V slices ----------------
__global__ __launch_bounds__(256) void slot_rt(const float* __restrict__ yws,
                                               const float* __restrict__ W_V,
                                               float* __restrict__ rtp)
{
    int b = blockIdx.x, c = blockIdx.y, tid = threadIdx.x;
    __shared__ float ysl[64];
    __shared__ float hsum[2][DB_];
    if (tid < 64) ysl[tid] = yws[(size_t)b*D_ + c*64 + tid];
    __syncthreads();
    int d = tid & 127, h = tid >> 7;
    float acc = 0.f;
    int e0 = h*32;
    #pragma unroll 8
    for (int e = e0; e < e0 + 32; e++)
        acc += ysl[e] * W_V[(size_t)(c*64 + e)*DB_ + d];
    hsum[h][d] = acc;
    __syncthreads();
    if (tid < DB_) rtp[((size_t)b*8 + c)*DB_ + tid] = hsum[0][tid] + hsum[1][tid];
}

// ---------------- slot_w1 (grid (B,16), 256thr): skv / gp1 / gp2 dots (independent) -------
__global__ __launch_bounds__(256) void slot_w1(
    const float* __restrict__ slots_in, const float* __restrict__ rtp,
    const float* __restrict__ W_K_slot, const float* __restrict__ skb,
    const float* __restrict__ Wg,
    float* __restrict__ skvw, float* __restrict__ gp1w, float* __restrict__ gp2w)
{
    int b = blockIdx.x, dc = blockIdx.y * 8, tid = threadIdx.x;
    __shared__ float sl[K_][DB_];
    __shared__ float Rt[DB_];
    __shared__ float w0s[DB_][9], w1s[DB_][9], w2s[DB_][9];
    __shared__ float parA[224], parB[224], parC[32];
    for (int p = tid; p < K_*DB_; p += 256) sl[p>>7][p&127] = slots_in[(size_t)b*K_*DB_ + p];
    if (tid < DB_) {
        float a = 0.f;
        #pragma unroll
        for (int c = 0; c < 8; c++) a += rtp[((size_t)b*8 + c)*DB_ + tid];
        Rt[tid] = a;
    }
    if (tid < 128) {
        float4 a0 = *(const float4*)&W_K_slot[(size_t)tid*DB_ + dc];
        float4 a1 = *(const float4*)&W_K_slot[(size_t)tid*DB_ + dc + 4];
        w0s[tid][0]=a0.x; w0s[tid][1]=a0.y; w0s[tid][2]=a0.z; w0s[tid][3]=a0.w;
        w0s[tid][4]=a1.x; w0s[tid][5]=a1.y; w0s[tid][6]=a1.z; w0s[tid][7]=a1.w;
        float4 b0 = *(const float4*)&Wg[(size_t)tid*DB_ + dc];
        float4 b1 = *(const float4*)&Wg[(size_t)tid*DB_ + dc + 4];
        w1s[tid][0]=b0.x; w1s[tid][1]=b0.y; w1s[tid][2]=b0.z; w1s[tid][3]=b0.w;
        w1s[tid][4]=b1.x; w1s[tid][5]=b1.y; w1s[tid][6]=b1.z; w1s[tid][7]=b1.w;
        float4 c0 = *(const float4*)&Wg[(size_t)(DB_ + tid)*DB_ + dc];
        float4 c1 = *(const float4*)&Wg[(size_t)(DB_ + tid)*DB_ + dc + 4];
        w2s[tid][0]=c0.x; w2s[tid][1]=c0.y; w2s[tid][2]=c0.z; w2s[tid][3]=c0.w;
        w2s[tid][4]=c1.x; w2s[tid][5]=c1.y; w2s[tid][6]=c1.z; w2s[tid][7]=c1.w;
    }
    __syncthreads();
    if (tid < 224) {
        int k = tid >> 5, rem = tid & 31, dloc = rem >> 2, e4 = rem & 3;
        float a0 = 0.f, a1 = 0.f;
        int e0 = e4*32;
        #pragma unroll 8
        for (int e = e0; e < e0+32; e++) {
            float sv = sl[k][e];
            a0 += sv * w0s[e][dloc];
            a1 += sv * w1s[e][dloc];
        }
        parA[tid] = a0; parB[tid] = a1;
    } else {
        int t2 = tid - 224;
        int dloc = t2 >> 2, e4 = t2 & 3;
        float a = 0.f;
        int e0 = e4*32;
        #pragma unroll 8
        for (int e = e0; e < e0+32; e++) a += Rt[e] * w2s[e][dloc];
        parC[t2] = a;
    }
    __syncthreads();
    if (tid < 56) {
        int k = tid >> 3, dloc = tid & 7;
        int base = k*32 + dloc*4;
        float a0 = parA[base] + parA[base+1] + parA[base+2] + parA[base+3];
        float a1 = parB[base] + parB[base+1] + parB[base+2] + parB[base+3];
        int d = dc + dloc;
        skvw[((size_t)b*K_ + k)*DB_ + d] = (a0 + skb[k*DB_ + d]) * Rt[d];
        gp1w[((size_t)b*K_ + k)*DB_ + d] = a1;
    } else if (tid < 64) {
        int dloc = tid - 56;
        int base = dloc*4;
        gp2w[(size_t)b*DB_ + dc + dloc] = parC[base] + parC[base+1] + parC[base+2] + parC[base+3];
    }
}

// ---------------- slot_w2 (grid B, 256thr): compat softmax + gate + upd + LN --------------
__global__ __launch_bounds__(256) void slot_w2(
    const float* __restrict__ slots_in, const float* __restrict__ rtp,
    const float* __restrict__ skvw, const float* __restrict__ gp1w,
    const float* __restrict__ gp2w, const float* __restrict__ Wgb,
    const float* __restrict__ lnw, const float* __restrict__ lnb,
    const float* __restrict__ temps,
    float* __restrict__ updw, float* __restrict__ bnw)
{
    int b = blockIdx.x, tid = threadIdx.x;
    __shared__ float sl[K_][DB_], Rt[DB_], upd[K_][DB_];
    __shared__ float compat[K_], swv[K_], mu7[K_], rs7[K_];
    for (int p = tid; p < K_*DB_; p += 256) sl[p>>7][p&127] = slots_in[(size_t)b*K_*DB_ + p];
    if (tid < DB_) {
        float a = 0.f;
        #pragma unroll
        for (int c = 0; c < 8; c++) a += rtp[((size_t)b*8 + c)*DB_ + tid];
        Rt[tid] = a;
    }
    __syncthreads();
    int g = tid >> 5, l32 = tid & 31;
    if (g < K_) {
        float a = 0.f;
        #pragma unroll
        for (int r = 0; r < 4; r++) a += skvw[((size_t)b*K_ + g)*DB_ + l32 + r*32];
        #pragma unroll
        for (int off = 16; off; off >>= 1) a += __shfl_xor(a, off);
        if (l32 == 0) compat[g] = a * SCALE_ * softplusf(temps[g]);
    }
    __syncthreads();
    if (tid == 0) {
        float m = compat[0];
        for (int k = 1; k < K_; k++) m = fmaxf(m, compat[k]);
        float ssum = 0.f;
        for (int k = 0; k < K_; k++) { float e = expf(compat[k]-m); swv[k] = e; ssum += e; }
        for (int k = 0; k < K_; k++) swv[k] /= ssum;
    }
    __syncthreads();
    #pragma unroll
    for (int r = 0; r < 4; r++) {
        int idx = tid + r*256;
        if (idx < K_*DB_) {
            int k = idx >> 7, d = idx & 127;
            float pre = gp1w[(size_t)b*K_*DB_ + idx] + swv[k]*gp2w[(size_t)b*DB_ + d] + Wgb[d];
            float gg = 1.f / (1.f + expf(-pre));
            float u = (1.f - gg)*sl[k][d] + gg*(swv[k]*Rt[d]);
            upd[k][d] = u;
            updw[(size_t)b*K_*DB_ + idx] = u;
        }
    }
    __syncthreads();
    if (g < K_) {
        float s = 0.f, ss = 0.f;
        #pragma unroll
        for (int r = 0; r < 4; r++) { float v = upd[g][l32 + r*32]; s += v; ss += v*v; }
        #pragma unroll
        for (int off = 16; off; off >>= 1) { s += __shfl_xor(s, off); ss += __shfl_xor(ss, off); }
        if (l32 == 0) {
            float mu = s / (float)DB_;
            mu7[g] = mu;
            rs7[g] = rsqrtf(ss/(float)DB_ - mu*mu + 1e-5f);
        }
    }
    __syncthreads();
    #pragma unroll
    for (int r = 0; r < 4; r++) {
        int idx = tid + r*256;
        if (idx < K_*DB_) {
            int k = idx >> 7, d = idx & 127;
            bnw[(size_t)b*K_*DB_ + idx] = (upd[k][d] - mu7[k])*rs7[k]*lnw[d] + lnb[d];
        }
    }
}

// ---------------- slot_qkv (grid (B,12), 256thr): Bn @ Ws{Q,K,V} slices -------------------
__global__ __launch_bounds__(256) void slot_qkv(const float* __restrict__ bnw,
    const float* __restrict__ WsQ, const float* __restrict__ WsK, const float* __restrict__ WsV,
    float* __restrict__ qkvw)
{
    int b = blockIdx.x, m = blockIdx.y >> 2, dc = (blockIdx.y & 3) * 32, tid = threadIdx.x;
    const float* W = (m == 0) ? WsQ : (m == 1) ? WsK : WsV;
    __shared__ float Bn[K_][DB_];
    __shared__ float ws[DB_][32];
    for (int p = tid; p < K_*DB_; p += 256) Bn[p>>7][p&127] = bnw[(size_t)b*K_*DB_ + p];
    #pragma unroll
    for (int i = 0; i < 16; i++) {
        int idx = tid + i*256;
        int row = idx >> 5, col = idx & 31;
        ws[row][col] = W[(size_t)row*DB_ + dc + col];
    }
    __syncthreads();
    if (tid < 224) {
        int k = tid >> 5, dloc = tid & 31;
        float a = 0.f;
        #pragma unroll 8
        for (int e = 0; e < DB_; e++) a += Bn[k][e] * ws[e][dloc];
        qkvw[(((size_t)m*B_ + b)*K_ + k)*DB_ + dc + dloc] = a;
    }
}

// ---------------- slot_fin (grid B, 512thr): sa + ctx + outputs + loss partials -----------
__global__ __launch_bounds__(512) void slot_fin(
    const float* __restrict__ slots_in, const float* __restrict__ updw,
    const float* __restrict__ qkvw, const float* __restrict__ lambda_,
    float* __restrict__ snws, float* __restrict__ out_slots,
    float* __restrict__ lpP, float* __restrict__ lpD)
{
    int b = blockIdx.x, tid = threadIdx.x;
    int lane = tid & 63, wvi = tid >> 6;    // 8 waves
    __shared__ float upd[K_][DB_], qq[K_][DB_], kk2[K_][DB_], vv[K_][DB_], sl[K_][DB_], snsh[K_][DB_];
    __shared__ float sa[K_][K_], nr7[K_], ldv[K_];
    __shared__ float pf[512];
    for (int p = tid; p < K_*DB_; p += 512) {
        int k = p >> 7, d = p & 127;
        upd[k][d] = updw[(size_t)b*K_*DB_ + p];
        qq[k][d]  = qkvw[(((size_t)0*B_ + b)*K_*DB_) + p];
        kk2[k][d] = qkvw[(((size_t)1*B_ + b)*K_*DB_) + p];
        vv[k][d]  = qkvw[(((size_t)2*B_ + b)*K_*DB_) + p];
        sl[k][d]  = slots_in[(size_t)b*K_*DB_ + p];
    }
    __syncthreads();
    if (wvi < K_) {
        int j = lane >> 3, s = lane & 7;
        float acc = 0.f;
        if (j < K_) {
            int e0 = s * 16;
            for (int e = e0; e < e0 + 16; e++) acc += qq[wvi][e] * kk2[j][e];
        }
        #pragma unroll
        for (int off = 4; off; off >>= 1) acc += __shfl_xor(acc, off, 8);
        if (s == 0 && j < K_) sa[wvi][j] = acc * SCALE_;
    }
    __syncthreads();
    if (tid < K_) {
        float m = sa[tid][0];
        for (int j = 1; j < K_; j++) m = fmaxf(m, sa[tid][j]);
        float ssum = 0.f;
        for (int j = 0; j < K_; j++) { float e = expf(sa[tid][j]-m); sa[tid][j] = e; ssum += e; }
        for (int j = 0; j < K_; j++) sa[tid][j] /= ssum;
    }
    __syncthreads();
    float dsq = 0.f;
    #pragma unroll
    for (int r = 0; r < 2; r++) {
        int idx = tid + r*512;
        if (idx < K_*DB_) {
            int k = idx >> 7, d = idx & 127;
            float lam = tanhf(lambda_[d]);
            lam = fminf(fmaxf(lam, -0.5f), 0.5f);
            float c = 0.f;
            #pragma unroll
            for (int j = 0; j < K_; j++) c += sa[k][j] * vv[j][d];
            float sn = upd[k][d] + c * lam;
            snsh[k][d] = sn;
            snws[(size_t)b*K_*DB_ + idx] = sn;
            out_slots[(size_t)b*K_*DB_ + idx] = sn;
            float ddf = sn - sl[k][d];
            dsq += ddf*ddf;
        }
    }
    __syncthreads();
    pf[tid] = dsq;
    if (wvi < K_) {
        float a0 = snsh[wvi][lane], a1 = snsh[wvi][lane + 64];
        float ss = a0*a0 + a1*a1;
        #pragma unroll
        for (int off = 32; off; off >>= 1) ss += __shfl_xor(ss, off);
        if (lane == 0) nr7[wvi] = fmaxf(sqrtf(ss), 1e-12f);
    }
    __syncthreads();
    if (wvi == 0) {
        float s = 0.f;
        #pragma unroll
        for (int q = 0; q < 8; q++) s += pf[lane + q*64];
        #pragma unroll
        for (int off = 32; off; off >>= 1) s += __shfl_xor(s, off);
        if (lane == 0) lpP[b] = s;
    }
    if (wvi >= 1 && wvi <= K_) {
        int q = wvi - 1;
        float accq = 0.f;
        for (int j = 0; j < K_; j++) {
            if (j == q) continue;
            float dt = snsh[q][lane]*snsh[j][lane] + snsh[q][lane+64]*snsh[j][lane+64];
            #pragma unroll
            for (int off = 32; off; off >>= 1) dt += __shfl_xor(dt, off);
            float cs = dt / (nr7[q] * nr7[j]);
            accq += cs*cs;
        }
        if (lane == 0) ldv[q] = accq;
    }
    __syncthreads();
    if (tid == 0) {
        float s = 0.f;
        for (int q = 0; q < K_; q++) s += ldv[q];
        lpD[b] = s;
    }
}

// ---------------- kq & vg (+basis inline, +loss finalize): grid (B, K) ----------------
__global__ __launch_bounds__(256) void kqvg_kernel(
    const float* __restrict__ sn, const float* __restrict__ WKr,
    const float* __restrict__ WQr, const float* __restrict__ WVr,
    const float* __restrict__ rc, const float* __restrict__ w0p,
    const float* __restrict__ lpP, const float* __restrict__ lpD,
    float* __restrict__ kq, float* __restrict__ vg, float* __restrict__ loss_out)
{
    int b = blockIdx.x, k = blockIdx.y, tid = threadIdx.x;
    if (b == 0 && k == 0 && tid == 0) {
        float s = 0.f, s2 = 0.f;
        for (int bb = 0; bb < B_; bb++) { s += lpP[bb]; s2 += lpD[bb]; }
        loss_out[0] = s / (float)(B_*K_*DB_);
        loss_out[1] = s2 / (float)(B_*(K_*K_-K_));
    }
    float P = 0.f, Q = 0.f;
    #pragma unroll
    for (int c = 0; c < 8; c++) {
        P += w0p[((size_t)b*8 + c)*2 + 0];
        Q += w0p[((size_t)b*8 + c)*2 + 1];
    }
    float pm = sqrtf(P), qm2 = sqrtf(Q);
    float tot = pm + qm2 + 1e-6f;
    float b1 = pm / tot, b2 = qm2 / tot;

    __shared__ float sl[DB_], kr[DB_];
    if (tid < DB_) sl[tid] = sn[((size_t)b*K_ + k)*DB_ + tid];
    __syncthreads();
    if (tid < DB_) {
        float a = 0.f;
        for (int e = 0; e < DB_; e++) a += sl[e] * WKr[(size_t)e*DB_ + tid];
        kr[tid] = a;
    }
    __syncthreads();
    #pragma unroll
    for (int rep = 0; rep < 2; rep++) {
        int e = tid + rep*256;
        float a = 0.f;
        const float* wq = WQr + (size_t)e*DB_;
        for (int d = 0; d < DB_; d++) a += kr[d] * wq[d];
        kq[((size_t)b*K_ + k)*D_ + e] = a;
    }
    #pragma unroll
    for (int rep = 0; rep < 2; rep++) {
        int dd = tid + rep*256;
        float a = 0.f;
        for (int e = 0; e < DB_; e++) a += sl[e] * WVr[(size_t)e*D_ + dd];
        float gpre = rc[((size_t)k*3 + 0)*D_ + dd] + b1*rc[((size_t)k*3 + 1)*D_ + dd] + b2*rc[((size_t)k*3 + 2)*D_ + dd];
        float g = tanhf(gpre);
        g = fminf(fmaxf(g, -0.5f), 0.5f);
        vg[((size_t)b*K_ + k)*D_ + dd] = a * g;
    }
}

// ---------------- z: softmax over 7 slots + weighted combine ----------------
__global__ __launch_bounds__(256) void z_kernel(const float* __restrict__ Xr,
                                                const float* __restrict__ kq,
                                                const float* __restrict__ vg,
                                                float* __restrict__ z)
{
    int b = blockIdx.x;
    int t0 = blockIdx.y * 64;
    __shared__ float kqs[K_][D_];
    __shared__ float vgs[K_][D_];
    int tid = threadIdx.x;
    for (int p = tid; p < K_*D_; p += 256) {
        kqs[p>>9][p&511] = kq[(size_t)b*K_*D_ + p];
        vgs[p>>9][p&511] = vg[(size_t)b*K_*D_ + p];
    }
    __syncthreads();
    int lane = tid & 63, w = tid >> 6;
    for (int it = 0; it < 16; it++) {
        int t = t0 + w*16 + it;
        const float* x = Xr + ((size_t)b*T_ + t)*D_;
        float xr[8];
        float s[K_] = {0,0,0,0,0,0,0};
        #pragma unroll
        for (int r = 0; r < 8; r++) {
            int e = lane + r*64;
            xr[r] = x[e];
            #pragma unroll
            for (int k = 0; k < K_; k++) s[k] += xr[r] * kqs[k][e];
        }
        #pragma unroll
        for (int k = 0; k < K_; k++)
            for (int off = 32; off; off >>= 1) s[k] += __shfl_xor(s[k], off);
        float sc[K_];
        float m = NEGINF;
        #pragma unroll
        for (int k = 0; k < K_; k++) { sc[k] = s[k] * SCALE_; m = fmaxf(m, sc[k]); }
        float p[K_], ssum = 0.f;
        #pragma unroll
        for (int k = 0; k < K_; k++) { p[k] = expf(sc[k] - m); ssum += p[k]; }
        float inv = 1.f / ssum;
        float* zp = z + ((size_t)b*T_ + t)*D_;
        #pragma unroll
        for (int r = 0; r < 8; r++) {
            int e = lane + r*64;
            float a = 0.f;
            #pragma unroll
            for (int k = 0; k < K_; k++) a += p[k] * vgs[k][e];
            zp[e] = a * inv;
        }
    }
}

extern "C" void kernel_launch(void* const* d_in, const int* in_sizes, int n_in,
                              void* d_out, int out_size, void* d_ws, size_t ws_size,
                              hipStream_t stream)
{
    const float* X_write = (const float*)d_in[0];
    const float* X_read  = (const float*)d_in[1];
    const float* slots   = (const float*)d_in[2];
    const float* W0      = (const float*)d_in[3];
    const float* lnw_w   = (const float*)d_in[4];
    const float* lnw_b   = (const float*)d_in[5];
    const float* W_V     = (const float*)d_in[6];
    const float* W_K_slot= (const float*)d_in[7];
    const float* skb     = (const float*)d_in[8];
    const float* Wg      = (const float*)d_in[9];
    const float* Wgb     = (const float*)d_in[10];
    const float* lns_w   = (const float*)d_in[11];
    const float* lns_b   = (const float*)d_in[12];
    const float* WsQ     = (const float*)d_in[13];
    const float* WsK     = (const float*)d_in[14];
    const float* WsV     = (const float*)d_in[15];
    const float* lambda_ = (const float*)d_in[16];
    const float* WQr     = (const float*)d_in[17];
    const float* WKr     = (const float*)d_in[18];
    const float* WVr     = (const float*)d_in[19];
    const float* rc      = (const float*)d_in[20];
    const float* temps   = (const float*)d_in[21];

    const size_t NXD = (size_t)B_*T_*D_;           // 16777216
    unsigned short* Xh  = (unsigned short*)d_ws;
    unsigned short* Xl  = Xh + NXD;
    float* Cf           = (float*)(Xl + NXD);      // f32 XW0, 64MB
    unsigned short* W0h = (unsigned short*)(Cf + NXD);
    unsigned short* W0l = W0h + (size_t)D_*D_;
    float* fscr  = (float*)(W0l + (size_t)D_*D_);
    float* qpart = fscr;                           // B*32*D = 262144
    float* w0p   = qpart + (size_t)B_*32*D_;       // 256
    float* snws  = w0p + 256;                      // 14336
    float* kq    = snws + (size_t)B_*K_*DB_;       // 57344
    float* vg    = kq + (size_t)B_*K_*D_;          // 57344
    float* cv    = vg + (size_t)B_*K_*D_;          // B*4096 = 65536
    int*   ci    = (int*)(cv + (size_t)B_*4096);   // 65536
    float* lpP   = (float*)(ci + (size_t)B_*4096); // 16
    float* lpD   = lpP + 16;                       // 16
    float* yws   = lpD + 16;                       // B*D = 8192
    float* rtp   = yws + (size_t)B_*D_;            // B*8*128 = 16384
    float* skvw  = rtp + (size_t)B_*8*DB_;         // B*896 = 14336
    float* gp1w  = skvw + (size_t)B_*K_*DB_;       // 14336
    float* gp2w  = gp1w + (size_t)B_*K_*DB_;       // B*128 = 2048
    float* updw  = gp2w + (size_t)B_*DB_;          // 14336
    float* bnw   = updw + (size_t)B_*K_*DB_;       // 14336
    float* qkvw  = bnw + (size_t)B_*K_*DB_;        // 3*B*896 = 43008

    float* z_out     = (float*)d_out;
    float* slots_out = z_out + NXD;
    float* loss_out  = slots_out + (size_t)B_*K_*DB_;
    float* sal       = z_out;    // scratch inside z region; consumed before z_kernel writes

    prep_kernel<<<dim3(4096 + 256 + 512), dim3(256), 0, stream>>>(
        X_write, lnw_w, lnw_b, Xh, Xl, W0, W0h, W0l, X_read, qpart);
    gemm_xw0_mfma<<<dim3(B_*T_/128, D_/128), dim3(256), 0, stream>>>(Xh, Xl, W0h, W0l, Cf);
    sal_mfma<<<dim3(B_, T_/64), dim3(256), 0, stream>>>(Xh, Xl, Cf, sal);
    topk_stage1<<<dim3(B_, 72), dim3(256), 0, stream>>>(sal, cv, ci, qpart, W0, w0p);
    slot_head<<<dim3(B_), dim3(512), 0, stream>>>(Xh, Xl, cv, ci, yws);
    slot_rt<<<dim3(B_, 8), dim3(256), 0, stream>>>(yws, W_V, rtp);
    slot_w1<<<dim3(B_, 16), dim3(256), 0, stream>>>(slots, rtp, W_K_slot, skb, Wg,
        skvw, gp1w, gp2w);
    slot_w2<<<dim3(B_), dim3(256), 0, stream>>>(slots, rtp, skvw, gp1w, gp2w, Wgb,
        lns_w, lns_b, temps, updw, bnw);
    slot_qkv<<<dim3(B_, 12), dim3(256), 0, stream>>>(bnw, WsQ, WsK, WsV, qkvw);
    slot_fin<<<dim3(B_), dim3(512), 0, stream>>>(slots, updw, qkvw, lambda_,
        snws, slots_out, lpP, lpD);
    kqvg_kernel<<<dim3(B_, K_), dim3(256), 0, stream>>>(snws, WKr, WQr, WVr, rc, w0p,
        lpP, lpD, kq, vg, loss_out);
    z_kernel<<<dim3(B_, T_/64), dim3(256), 0, stream>>>(X_read, kq, vg, z_out);
}

// Round 17
// 255.854 us; speedup vs baseline: 1.0630x; 1.0630x over previous
//
#include <hip/hip_runtime.h>
#include <math.h>

#define B_ 16
#define T_ 2048
#define D_ 512
#define DB_ 128
#define K_ 7
#define TOPK_ 16
#define WIN_ 64

static constexpr float SCALE_ = 0.08838834764831845f;   // 128^-0.5
static constexpr float PHI_ = 1.618033988749895f;
static constexpr float PSI_ = -0.6180339887498949f;
static constexpr float INV_DENOM_ = 0.4472135954999579f; // 1/(PHI-PSI)
static constexpr float NEGV = -1e30f;
static constexpr float NEGINF = -3.402823466e38f;
#define IMAXI 0x7FFFFFFF

typedef __attribute__((ext_vector_type(8))) __bf16 bf16x8;
typedef __attribute__((ext_vector_type(8))) unsigned short u16x8;
typedef __attribute__((ext_vector_type(4))) float f32x4;

__device__ inline float softplusf(float x){
    return fmaxf(x, 0.f) + log1pf(expf(-fabsf(x)));
}
__device__ inline unsigned short f2bf(float x){
    unsigned int u = __float_as_uint(x);
    unsigned int r = (u + 0x7FFFu + ((u >> 16) & 1u)) >> 16;
    return (unsigned short)r;
}
__device__ inline float bf2f(unsigned short h){
    return __uint_as_float(((unsigned int)h) << 16);
}
__device__ inline bf16x8 ld_bf8(const unsigned short* p){
    u16x8 r = *(const u16x8*)p;
    return __builtin_bit_cast(bf16x8, r);
}
__device__ inline unsigned int pkbf(float a, float b){
    unsigned int r;
    asm("v_cvt_pk_bf16_f32 %0, %1, %2" : "=v"(r) : "v"(a), "v"(b));
    return r;
}
typedef __attribute__((address_space(3))) unsigned int as3_u32;
typedef const __attribute__((address_space(1))) unsigned int as1_u32c;
__device__ inline void gload16(const void* g, void* l){
    __builtin_amdgcn_global_load_lds((as1_u32c*)g, (as3_u32*)l, 16, 0, 0);
}

// ---------------- prep: LN(X_write)->Xh/Xl (wave-per-row) | W0->hi/lo | qmean partials -----
__global__ __launch_bounds__(256) void prep_kernel(const float* __restrict__ X,
                                                   const float* __restrict__ w,
                                                   const float* __restrict__ b,
                                                   unsigned short* __restrict__ Xh,
                                                   unsigned short* __restrict__ Xl,
                                                   const float* __restrict__ W0,
                                                   unsigned short* __restrict__ Wh,
                                                   unsigned short* __restrict__ Wl,
                                                   const float* __restrict__ Xr,
                                                   float* __restrict__ qpart)
{
    int bx = blockIdx.x;
    int tid = threadIdx.x;
    if (bx < 4096) {
        int lane = tid & 63, wv = tid >> 6;
        int row = bx * 8 + wv * 2;
        float4 wv0 = *(const float4*)(w + lane*4);
        float4 wv1 = *(const float4*)(w + 256 + lane*4);
        float4 bv0 = *(const float4*)(b + lane*4);
        float4 bv1 = *(const float4*)(b + 256 + lane*4);
        #pragma unroll
        for (int rr = 0; rr < 2; rr++) {
            const float* x = X + (size_t)(row + rr) * D_;
            float4 v0 = *(const float4*)(x + lane*4);
            float4 v1 = *(const float4*)(x + 256 + lane*4);
            float s  = v0.x+v0.y+v0.z+v0.w + v1.x+v1.y+v1.z+v1.w;
            float ss = v0.x*v0.x+v0.y*v0.y+v0.z*v0.z+v0.w*v0.w
                     + v1.x*v1.x+v1.y*v1.y+v1.z*v1.z+v1.w*v1.w;
            #pragma unroll
            for (int off = 32; off; off >>= 1) { s += __shfl_xor(s, off); ss += __shfl_xor(ss, off); }
            float mu = s * (1.f/512.f);
            float rs = rsqrtf(ss*(1.f/512.f) - mu*mu + 1e-5f);
            float o0 = (v0.x - mu)*rs*wv0.x + bv0.x;
            float o1 = (v0.y - mu)*rs*wv0.y + bv0.y;
            float o2 = (v0.z - mu)*rs*wv0.z + bv0.z;
            float o3 = (v0.w - mu)*rs*wv0.w + bv0.w;
            float o4 = (v1.x - mu)*rs*wv1.x + bv1.x;
            float o5 = (v1.y - mu)*rs*wv1.y + bv1.y;
            float o6 = (v1.z - mu)*rs*wv1.z + bv1.z;
            float o7 = (v1.w - mu)*rs*wv1.w + bv1.w;
            unsigned short h0 = f2bf(o0), h1 = f2bf(o1), h2 = f2bf(o2), h3 = f2bf(o3);
            unsigned short h4 = f2bf(o4), h5 = f2bf(o5), h6 = f2bf(o6), h7 = f2bf(o7);
            uint2 hA; hA.x = (unsigned int)h0 | ((unsigned int)h1 << 16);
                      hA.y = (unsigned int)h2 | ((unsigned int)h3 << 16);
            uint2 hB; hB.x = (unsigned int)h4 | ((unsigned int)h5 << 16);
                      hB.y = (unsigned int)h6 | ((unsigned int)h7 << 16);
            uint2 lA; lA.x = (unsigned int)f2bf(o0 - bf2f(h0)) | ((unsigned int)f2bf(o1 - bf2f(h1)) << 16);
                      lA.y = (unsigned int)f2bf(o2 - bf2f(h2)) | ((unsigned int)f2bf(o3 - bf2f(h3)) << 16);
            uint2 lB; lB.x = (unsigned int)f2bf(o4 - bf2f(h4)) | ((unsigned int)f2bf(o5 - bf2f(h5)) << 16);
                      lB.y = (unsigned int)f2bf(o6 - bf2f(h6)) | ((unsigned int)f2bf(o7 - bf2f(h7)) << 16);
            unsigned short* xh = Xh + (size_t)(row + rr) * D_;
            unsigned short* xl = Xl + (size_t)(row + rr) * D_;
            *(uint2*)(xh + lane*4) = hA;
            *(uint2*)(xh + 256 + lane*4) = hB;
            *(uint2*)(xl + lane*4) = lA;
            *(uint2*)(xl + 256 + lane*4) = lB;
        }
    } else if (bx < 4352) {
        int gid = (bx - 4096) * 256 + tid;
        float4 v = ((const float4*)W0)[gid];
        unsigned short h0 = f2bf(v.x), h1 = f2bf(v.y), h2 = f2bf(v.z), h3 = f2bf(v.w);
        ushort4 hv = make_ushort4(h0, h1, h2, h3);
        ushort4 lv = make_ushort4(f2bf(v.x - bf2f(h0)), f2bf(v.y - bf2f(h1)),
                                  f2bf(v.z - bf2f(h2)), f2bf(v.w - bf2f(h3)));
        *(ushort4*)&Wh[(size_t)gid*4] = hv;
        *(ushort4*)&Wl[(size_t)gid*4] = lv;
    } else {
        int idx = bx - 4352;
        int b_ = idx >> 5, c = idx & 31;
        const float* base = Xr + ((size_t)(b_*T_ + c*64)) * D_;
        float s0 = 0.f, s1 = 0.f;
        for (int t = 0; t < 64; t++) {
            s0 += base[(size_t)t*D_ + tid];
            s1 += base[(size_t)t*D_ + tid + 256];
        }
        qpart[((size_t)b_*32 + c)*D_ + tid] = s0;
        qpart[((size_t)b_*32 + c)*D_ + tid + 256] = s1;
    }
}

// ---------------- XW0: bf16x3 MFMA, DOUBLE-BUFFERED gload_lds, swizzled LDS, f32 out -------
__global__ __launch_bounds__(256) void gemm_xw0_mfma(const unsigned short* __restrict__ Ah,
                                                     const unsigned short* __restrict__ Al,
                                                     const unsigned short* __restrict__ Wh,
                                                     const unsigned short* __restrict__ Wl,
                                                     float* __restrict__ Cf)
{
    __shared__ __align__(16) unsigned short sAh[2*128*32], sAl[2*128*32], sBh[2*128*32], sBl[2*128*32];
    int t0 = blockIdx.x * 128, d0 = blockIdx.y * 128;
    int tid = threadIdx.x;
    int lane = tid & 63, wid = tid >> 6;
    int wr = wid >> 1, wc = wid & 1;
    int fr = lane & 15;
    int kc2 = ((((lane >> 4) + (fr >> 1)) & 3) * 8);

    f32x4 acc[4][4];
    #pragma unroll
    for (int m = 0; m < 4; m++)
        #pragma unroll
        for (int n = 0; n < 4; n++) acc[m][n] = (f32x4){0.f,0.f,0.f,0.f};

    const unsigned short* gs = (wid==0) ? Ah : (wid==1) ? Al : (wid==2) ? Wh : Wl;
    unsigned short* lsA = (wid==0) ? sAh : (wid==1) ? sAl : (wid==2) ? sBh : sBl;
    int rowoff = (wid < 2) ? t0 : d0;
    int cch = ((lane & 3) - ((lane >> 3) & 3)) & 3;
    const unsigned short* gbase = gs + (size_t)(rowoff + (lane >> 2))*512 + cch*8;

    #pragma unroll
    for (int i = 0; i < 8; i++)
        gload16(gbase + (size_t)(16*i)*512 + 0, lsA + i*512);

    for (int t = 0; t < 16; t++) {
        int cur = t & 1;
        __syncthreads();
        if (t < 15) {
            unsigned short* ls = lsA + (cur^1)*(128*32);
            int kk = (t+1)*32;
            #pragma unroll
            for (int i = 0; i < 8; i++)
                gload16(gbase + (size_t)(16*i)*512 + kk, ls + i*512);
        }
        int bo = cur*(128*32);
        bf16x8 ahf[4], alf[4], bhf[4], blf[4];
        #pragma unroll
        for (int m = 0; m < 4; m++) {
            int r = bo + (wr*64 + m*16 + fr)*32 + kc2;
            ahf[m] = ld_bf8(&sAh[r]);
            alf[m] = ld_bf8(&sAl[r]);
        }
        #pragma unroll
        for (int n = 0; n < 4; n++) {
            int r = bo + (wc*64 + n*16 + fr)*32 + kc2;
            bhf[n] = ld_bf8(&sBh[r]);
            blf[n] = ld_bf8(&sBl[r]);
        }
        #pragma unroll
        for (int m = 0; m < 4; m++)
            #pragma unroll
            for (int n = 0; n < 4; n++) {
                acc[m][n] = __builtin_amdgcn_mfma_f32_16x16x32_bf16(bhf[n], ahf[m], acc[m][n], 0, 0, 0);
                acc[m][n] = __builtin_amdgcn_mfma_f32_16x16x32_bf16(bhf[n], alf[m], acc[m][n], 0, 0, 0);
                acc[m][n] = __builtin_amdgcn_mfma_f32_16x16x32_bf16(blf[n], ahf[m], acc[m][n], 0, 0, 0);
            }
    }

    #pragma unroll
    for (int m = 0; m < 4; m++) {
        int t = t0 + wr*64 + m*16 + fr;
        #pragma unroll
        for (int n = 0; n < 4; n++) {
            int dbase = d0 + wc*64 + n*16 + (lane >> 4)*4;
            *(f32x4*)&Cf[(size_t)t*512 + dbase] = acc[m][n];
        }
    }
}

// ---------------- sal: bf16x3 MFMA, swizzled LDS, issue-early global loads ----------------
__global__ __launch_bounds__(256) void sal_mfma(const unsigned short* __restrict__ Xh,
                                                const unsigned short* __restrict__ Xl,
                                                const float* __restrict__ Cf,
                                                float* __restrict__ sal)
{
    int b = blockIdx.x, i0 = blockIdx.y * 64;
    __shared__ __align__(16) unsigned short sAh[64*32], sAl[64*32], sBh[128*32], sBl[128*32];
    int tid = threadIdx.x;
    int lane = tid & 63, wcw = tid >> 6;
    int fr = lane & 15;
    int kc2 = ((((lane >> 4) + (fr >> 1)) & 3) * 8);

    const unsigned short* XhB = Xh + (size_t)b*T_*D_;
    const unsigned short* XlB = Xl + (size_t)b*T_*D_;
    const float* CfB = Cf + (size_t)b*T_*D_;

    f32x4 acc[4][2];
    #pragma unroll
    for (int m = 0; m < 4; m++) { acc[m][0] = (f32x4){0.f,0.f,0.f,0.f}; acc[m][1] = (f32x4){0.f,0.f,0.f,0.f}; }

    int ar = tid >> 2, ac = tid & 3;
    int aslot = (ac + (ar >> 1)) & 3;
    int brow = tid >> 1, bhh = tid & 1;
    int jrow = i0 - 64 + brow;

    uint4 rAh, rAl;
    float4 rB0[2], rB1[2];

    auto LOAD = [&](int kk){
        rAh = *(const uint4*)(XhB + (size_t)(i0 + ar)*512 + kk + ac*8);
        rAl = *(const uint4*)(XlB + (size_t)(i0 + ar)*512 + kk + ac*8);
        #pragma unroll
        for (int cc = 0; cc < 2; cc++) {
            int c = 2*bhh + cc;
            if (jrow >= 0) {
                const float* src = CfB + (size_t)jrow*512 + kk + c*8;
                rB0[cc] = *(const float4*)src;
                rB1[cc] = *(const float4*)(src + 4);
            } else {
                rB0[cc] = make_float4(0.f,0.f,0.f,0.f);
                rB1[cc] = make_float4(0.f,0.f,0.f,0.f);
            }
        }
    };
    auto WRITE = [&](){
        *(uint4*)&sAh[ar*32 + aslot*8] = rAh;
        *(uint4*)&sAl[ar*32 + aslot*8] = rAl;
        #pragma unroll
        for (int cc = 0; cc < 2; cc++) {
            int c = 2*bhh + cc;
            int slot = (c + (brow >> 1)) & 3;
            uint4 hv, lv;
            float4 v0 = rB0[cc], v1 = rB1[cc];
            unsigned int h01 = pkbf(v0.x, v0.y), h23 = pkbf(v0.z, v0.w);
            unsigned int h45 = pkbf(v1.x, v1.y), h67 = pkbf(v1.z, v1.w);
            float r0 = v0.x - __uint_as_float(h01 << 16);
            float r1 = v0.y - __uint_as_float(h01 & 0xFFFF0000u);
            float r2 = v0.z - __uint_as_float(h23 << 16);
            float r3 = v0.w - __uint_as_float(h23 & 0xFFFF0000u);
            float r4 = v1.x - __uint_as_float(h45 << 16);
            float r5 = v1.y - __uint_as_float(h45 & 0xFFFF0000u);
            float r6 = v1.z - __uint_as_float(h67 << 16);
            float r7 = v1.w - __uint_as_float(h67 & 0xFFFF0000u);
            hv.x = h01; hv.y = h23; hv.z = h45; hv.w = h67;
            lv.x = pkbf(r0, r1); lv.y = pkbf(r2, r3); lv.z = pkbf(r4, r5); lv.w = pkbf(r6, r7);
            *(uint4*)&sBh[brow*32 + slot*8] = hv;
            *(uint4*)&sBl[brow*32 + slot*8] = lv;
        }
    };

    LOAD(0);
    for (int t = 0; t < 16; t++) {
        WRITE();
        __syncthreads();
        int kkn = (t+1)*32;
        bf16x8 ahf[4], alf[4], bhf[2], blf[2];
        #pragma unroll
        for (int m = 0; m < 4; m++) {
            int r = (m*16 + fr)*32 + kc2;
            ahf[m] = ld_bf8(&sAh[r]);
            alf[m] = ld_bf8(&sAl[r]);
        }
        #pragma unroll
        for (int n = 0; n < 2; n++) {
            int r = (wcw*32 + n*16 + fr)*32 + kc2;
            bhf[n] = ld_bf8(&sBh[r]);
            blf[n] = ld_bf8(&sBl[r]);
        }
        if (t < 15) LOAD(kkn);
        #pragma unroll
        for (int m = 0; m < 4; m++)
            #pragma unroll
            for (int n = 0; n < 2; n++) {
                acc[m][n] = __builtin_amdgcn_mfma_f32_16x16x32_bf16(ahf[m], bhf[n], acc[m][n], 0, 0, 0);
                acc[m][n] = __builtin_amdgcn_mfma_f32_16x16x32_bf16(ahf[m], blf[n], acc[m][n], 0, 0, 0);
                acc[m][n] = __builtin_amdgcn_mfma_f32_16x16x32_bf16(alf[m], bhf[n], acc[m][n], 0, 0, 0);
            }
        __syncthreads();
    }

    float* salB = sal + (size_t)b*T_*WIN_;
    #pragma unroll
    for (int m = 0; m < 4; m++) {
        #pragma unroll
        for (int n = 0; n < 2; n++) {
            int jl = wcw*32 + n*16 + fr;
            #pragma unroll
            for (int r = 0; r < 4; r++) {
                int il = m*16 + (lane >> 4)*4 + r;
                int o = il - jl + 64;
                if (o >= 1 && o <= 64) {
                    int jg = i0 - 64 + jl;
                    salB[(size_t)(i0 + il)*WIN_ + (o - 1)] = (jg >= 0) ? acc[m][n][r] : NEGV;
                }
            }
        }
    }
}

// ---------------- top-16 stage 1 (y<64, static-index lists) + w0q partials (y>=64) --------
__global__ __launch_bounds__(256) void topk_stage1(const float* __restrict__ sal,
                                                   float* __restrict__ cv, int* __restrict__ ci,
                                                   const float* __restrict__ qpart,
                                                   const float* __restrict__ W0,
                                                   float* __restrict__ w0p)
{
    int b = blockIdx.x, tid = threadIdx.x;
    if (blockIdx.y >= 64) {
        int c = blockIdx.y - 64;
        __shared__ float qm[D_];
        for (int p = tid; p < D_; p += 256) {
            float s = 0.f;
            for (int cc = 0; cc < 32; cc++) s += qpart[((size_t)b*32 + cc)*D_ + p];
            qm[p] = s * (1.f/2048.f);
        }
        __syncthreads();
        int w = tid >> 6, lane = tid & 63;
        float ph = 0.f, ps = 0.f;
        for (int r = 0; r < 16; r++) {
            int d = c*64 + w*16 + r;
            const float* wr = W0 + (size_t)d*D_;
            float s = 0.f;
            #pragma unroll
            for (int q = 0; q < 8; q++) s += qm[lane + q*64] * wr[lane + q*64];
            #pragma unroll
            for (int off = 32; off; off >>= 1) s += __shfl_xor(s, off);
            float phi = (s - PSI_*qm[d]) * INV_DENOM_;
            float psi = (PHI_*qm[d] - s) * INV_DENOM_;
            ph += phi*phi; ps += psi*psi;
        }
        __shared__ float shp[4], shs[4];
        if (lane == 0) { shp[w] = ph; shs[w] = ps; }
        __syncthreads();
        if (tid == 0) {
            w0p[((size_t)b*8 + c)*2 + 0] = shp[0]+shp[1]+shp[2]+shp[3];
            w0p[((size_t)b*8 + c)*2 + 1] = shs[0]+shs[1]+shs[2]+shs[3];
        }
        return;
    }
    int c = blockIdx.y;
    const float* s = sal + (size_t)b*(T_*WIN_) + (size_t)c*2048;
    int base = c*2048;
    int lane = tid & 63, wvi = tid >> 6;
    float v0=NEGINF,v1=NEGINF,v2=NEGINF,v3=NEGINF,v4=NEGINF,v5=NEGINF,v6=NEGINF,v7=NEGINF;
    int   i0=IMAXI, i1=IMAXI, i2=IMAXI, i3=IMAXI, i4=IMAXI, i5=IMAXI, i6=IMAXI, i7=IMAXI;
    #pragma unroll
    for (int r = 0; r < 8; r++) {
        int p = tid + r*256;
        float v = s[p];
        int idx = base + p;
        if (v > v7 || (v == v7 && idx < i7)) {
            bool b6 = (v > v6) || (v == v6 && idx < i6);
            bool b5 = (v > v5) || (v == v5 && idx < i5);
            bool b4 = (v > v4) || (v == v4 && idx < i4);
            bool b3 = (v > v3) || (v == v3 && idx < i3);
            bool b2 = (v > v2) || (v == v2 && idx < i2);
            bool b1 = (v > v1) || (v == v1 && idx < i1);
            bool b0 = (v > v0) || (v == v0 && idx < i0);
            float n7 = b6 ? v6 : v;             int m7 = b6 ? i6 : idx;
            float n6 = b6 ? (b5 ? v5 : v) : v6; int m6 = b6 ? (b5 ? i5 : idx) : i6;
            float n5 = b5 ? (b4 ? v4 : v) : v5; int m5 = b5 ? (b4 ? i4 : idx) : i5;
            float n4 = b4 ? (b3 ? v3 : v) : v4; int m4 = b4 ? (b3 ? i3 : idx) : i4;
            float n3 = b3 ? (b2 ? v2 : v) : v3; int m3 = b3 ? (b2 ? i2 : idx) : i3;
            float n2 = b2 ? (b1 ? v1 : v) : v2; int m2 = b2 ? (b1 ? i1 : idx) : i2;
            float n1 = b1 ? (b0 ? v0 : v) : v1; int m1 = b1 ? (b0 ? i0 : idx) : i1;
            float n0 = b0 ? v : v0;             int m0 = b0 ? idx : i0;
            v7=n7;i7=m7; v6=n6;i6=m6; v5=n5;i5=m5; v4=n4;i4=m4;
            v3=n3;i3=m3; v2=n2;i2=m2; v1=n1;i1=m1; v0=n0;i0=m0;
        }
    }
    float* cvo = cv + (((size_t)b*64 + c)*64) + wvi*16;
    int*   cio = ci + (((size_t)b*64 + c)*64) + wvi*16;
    for (int r = 0; r < 16; r++) {
        float bv = v0; int bi = i0;
        float wv_ = bv; int wi = bi;
        #pragma unroll
        for (int off = 1; off < 64; off <<= 1) {
            float vx = __shfl_xor(wv_, off);
            int   ix = __shfl_xor(wi, off);
            if (vx > wv_ || (vx == wv_ && ix < wi)) { wv_ = vx; wi = ix; }
        }
        if (bv == wv_ && bi == wi) {
            v0=v1;i0=i1; v1=v2;i1=i2; v2=v3;i2=i3; v3=v4;i3=i4;
            v4=v5;i4=i5; v5=v6;i5=i6; v6=v7;i6=i7; v7=NEGINF;i7=IMAXI;
        }
        if (lane == 0) { cvo[r] = wv_; cio[r] = wi; }
    }
}

// ---------------- slot_head (grid B, 512thr): topk merge + alpha + y -----------------------
__global__ __launch_bounds__(512) void slot_head(
    const unsigned short* __restrict__ Xh, const unsigned short* __restrict__ Xl,
    const float* __restrict__ cv, const int* __restrict__ ci,
    float* __restrict__ yws)
{
    int b = blockIdx.x, tid = threadIdx.x;
    int lane = tid & 63, wvi = tid >> 6;      // 8 waves
    __shared__ float scv[128]; __shared__ int sci[128];
    __shared__ float tvv[16]; __shared__ int tii[16];
    __shared__ float alpha[16]; __shared__ int tis[16], tjs[16];

    const float* cvb = cv + (size_t)b*4096;
    const int*   cib = ci + (size_t)b*4096;
    float v0=NEGINF,v1=NEGINF,v2=NEGINF,v3=NEGINF,v4=NEGINF,v5=NEGINF,v6=NEGINF,v7=NEGINF;
    int   i0=IMAXI, i1=IMAXI, i2=IMAXI, i3=IMAXI, i4=IMAXI, i5=IMAXI, i6=IMAXI, i7=IMAXI;
    #pragma unroll
    for (int r = 0; r < 8; r++) {
        int p = tid + r*512;
        float v = cvb[p];
        int idx = cib[p];
        if (v > v7 || (v == v7 && idx < i7)) {
            bool b6 = (v > v6) || (v == v6 && idx < i6);
            bool b5 = (v > v5) || (v == v5 && idx < i5);
            bool b4 = (v > v4) || (v == v4 && idx < i4);
            bool b3 = (v > v3) || (v == v3 && idx < i3);
            bool b2 = (v > v2) || (v == v2 && idx < i2);
            bool b1 = (v > v1) || (v == v1 && idx < i1);
            bool b0 = (v > v0) || (v == v0 && idx < i0);
            float n7 = b6 ? v6 : v;             int m7 = b6 ? i6 : idx;
            float n6 = b6 ? (b5 ? v5 : v) : v6; int m6 = b6 ? (b5 ? i5 : idx) : i6;
            float n5 = b5 ? (b4 ? v4 : v) : v5; int m5 = b5 ? (b4 ? i4 : idx) : i5;
            float n4 = b4 ? (b3 ? v3 : v) : v4; int m4 = b4 ? (b3 ? i3 : idx) : i4;
            float n3 = b3 ? (b2 ? v2 : v) : v3; int m3 = b3 ? (b2 ? i2 : idx) : i3;
            float n2 = b2 ? (b1 ? v1 : v) : v2; int m2 = b2 ? (b1 ? i1 : idx) : i2;
            float n1 = b1 ? (b0 ? v0 : v) : v1; int m1 = b1 ? (b0 ? i0 : idx) : i1;
            float n0 = b0 ? v : v0;             int m0 = b0 ? idx : i0;
            v7=n7;i7=m7; v6=n6;i6=m6; v5=n5;i5=m5; v4=n4;i4=m4;
            v3=n3;i3=m3; v2=n2;i2=m2; v1=n1;i1=m1; v0=n0;i0=m0;
        }
    }
    for (int r = 0; r < 16; r++) {
        float bv = v0; int bi = i0;
        float wv_ = bv; int wi = bi;
        #pragma unroll
        for (int off = 1; off < 64; off <<= 1) {
            float vx = __shfl_xor(wv_, off);
            int   ix = __shfl_xor(wi, off);
            if (vx > wv_ || (vx == wv_ && ix < wi)) { wv_ = vx; wi = ix; }
        }
        if (bv == wv_ && bi == wi) {
            v0=v1;i0=i1; v1=v2;i1=i2; v2=v3;i2=i3; v3=v4;i3=i4;
            v4=v5;i4=i5; v5=v6;i5=i6; v6=v7;i6=i7; v7=NEGINF;i7=IMAXI;
        }
        if (lane == 0) { scv[wvi*16 + r] = wv_; sci[wvi*16 + r] = wi; }
    }
    __syncthreads();
    if (wvi == 0) {
        float a0 = scv[lane], a1 = scv[lane + 64];
        int   e0 = sci[lane], e1 = sci[lane + 64];
        bool sw = (a1 > a0) || (a1 == a0 && e1 < e0);
        float u0 = sw ? a1 : a0; int j0 = sw ? e1 : e0;
        float u1 = sw ? a0 : a1; int j1 = sw ? e0 : e1;
        for (int r = 0; r < 16; r++) {
            float bv = u0; int bi = j0;
            float wv_ = bv; int wi = bi;
            #pragma unroll
            for (int off = 1; off < 64; off <<= 1) {
                float vx = __shfl_xor(wv_, off);
                int   ix = __shfl_xor(wi, off);
                if (vx > wv_ || (vx == wv_ && ix < wi)) { wv_ = vx; wi = ix; }
            }
            if (bv == wv_ && bi == wi) { u0 = u1; j0 = j1; u1 = NEGINF; j1 = IMAXI; }
            if (lane == 0) { tvv[r] = wv_; tii[r] = wi; }
        }
    }
    __syncthreads();
    if (tid < 16) {
        float v = tvv[tid];
        int flat = tii[tid];
        tis[tid] = flat >> 6;
        tjs[tid] = (flat >> 6) - ((flat & 63) + 1);
        float m = v;
        #pragma unroll
        for (int off = 8; off; off >>= 1) m = fmaxf(m, __shfl_xor(m, off, 16));
        float e = expf(v - m);
        float s = e;
        #pragma unroll
        for (int off = 8; off; off >>= 1) s += __shfl_xor(s, off, 16);
        alpha[tid] = e / s;
    }
    __syncthreads();
    {
        float acc = 0.f;
        #pragma unroll
        for (int k = 0; k < 16; k++) {
            int i = tis[k], j = tjs[k];
            float xi = bf2f(Xh[((size_t)b*T_ + i)*D_ + tid]) + bf2f(Xl[((size_t)b*T_ + i)*D_ + tid]);
            float xj = bf2f(Xh[((size_t)b*T_ + j)*D_ + tid]) + bf2f(Xl[((size_t)b*T_ + j)*D_ + tid]);
            acc += alpha[k] * (xi - xj);
        }
        yws[(size_t)b*D_ + tid] = acc;
    }
}

// ---------------- slot_rt (grid (B,8)): Rt partials over 64-row W_V slices ----------------
__global__ __launch_bounds__(256) void slot_rt(const float* __restrict__ yws,
                                               const float* __restrict__ W_V,
                                               float* __restrict__ rtp)
{
    int b = blockIdx.x, c = blockIdx.y, tid = threadIdx.x;
    __shared__ float ysl[64];
    __shared__ float hsum[2][DB_];
    if (tid < 64) ysl[tid] = yws[(size_t)b*D_ + c*64 + tid];
    __syncthreads();
    int d = tid & 127, h = tid >> 7;
    float acc = 0.f;
    int e0 = h*32;
    #pragma unroll 8
    for (int e = e0; e < e0 + 32; e++)
        acc += ysl[e] * W_V[(size_t)(c*64 + e)*DB_ + d];
    hsum[h][d] = acc;
    __syncthreads();
    if (tid < DB_) rtp[((size_t)b*8 + c)*DB_ + tid] = hsum[0][tid] + hsum[1][tid];
}

// ---------------- slot_w1 (grid (B,16), 256thr): skv / gp1 / gp2 dots (independent) -------
__global__ __launch_bounds__(256) void slot_w1(
    const float* __restrict__ slots_in, const float* __restrict__ rtp,
    const float* __restrict__ W_K_slot, const float* __restrict__ skb,
    const float* __restrict__ Wg,
    float* __restrict__ skvw, float* __restrict__ gp1w, float* __restrict__ gp2w)
{
    int b = blockIdx.x, dc = blockIdx.y * 8, tid = threadIdx.x;
    __shared__ float sl[K_][DB_];
    __shared__ float Rt[DB_];
    __shared__ float w0s[DB_][9], w1s[DB_][9], w2s[DB_][9];
    __shared__ float parA[224], parB[224], parC[32];
    for (int p = tid; p < K_*DB_; p += 256) sl[p>>7][p&127] = slots_in[(size_t)b*K_*DB_ + p];
    if (tid < DB_) {
        float a = 0.f;
        #pragma unroll
        for (int c = 0; c < 8; c++) a += rtp[((size_t)b*8 + c)*DB_ + tid];
        Rt[tid] = a;
    }
    if (tid < 128) {
        float4 a0 = *(const float4*)&W_K_slot[(size_t)tid*DB_ + dc];
        float4 a1 = *(const float4*)&W_K_slot[(size_t)tid*DB_ + dc + 4];
        w0s[tid][0]=a0.x; w0s[tid][1]=a0.y; w0s[tid][2]=a0.z; w0s[tid][3]=a0.w;
        w0s[tid][4]=a1.x; w0s[tid][5]=a1.y; w0s[tid][6]=a1.z; w0s[tid][7]=a1.w;
        float4 b0 = *(const float4*)&Wg[(size_t)tid*DB_ + dc];
        float4 b1 = *(const float4*)&Wg[(size_t)tid*DB_ + dc + 4];
        w1s[tid][0]=b0.x; w1s[tid][1]=b0.y; w1s[tid][2]=b0.z; w1s[tid][3]=b0.w;
        w1s[tid][4]=b1.x; w1s[tid][5]=b1.y; w1s[tid][6]=b1.z; w1s[tid][7]=b1.w;
        float4 c0 = *(const float4*)&Wg[(size_t)(DB_ + tid)*DB_ + dc];
        float4 c1 = *(const float4*)&Wg[(size_t)(DB_ + tid)*DB_ + dc + 4];
        w2s[tid][0]=c0.x; w2s[tid][1]=c0.y; w2s[tid][2]=c0.z; w2s[tid][3]=c0.w;
        w2s[tid][4]=c1.x; w2s[tid][5]=c1.y; w2s[tid][6]=c1.z; w2s[tid][7]=c1.w;
    }
    __syncthreads();
    if (tid < 224) {
        int k = tid >> 5, rem = tid & 31, dloc = rem >> 2, e4 = rem & 3;
        float a0 = 0.f, a1 = 0.f;
        int e0 = e4*32;
        #pragma unroll 8
        for (int e = e0; e < e0+32; e++) {
            float sv = sl[k][e];
            a0 += sv * w0s[e][dloc];
            a1 += sv * w1s[e][dloc];
        }
        parA[tid] = a0; parB[tid] = a1;
    } else {
        int t2 = tid - 224;
        int dloc = t2 >> 2, e4 = t2 & 3;
        float a = 0.f;
        int e0 = e4*32;
        #pragma unroll 8
        for (int e = e0; e < e0+32; e++) a += Rt[e] * w2s[e][dloc];
        parC[t2] = a;
    }
    __syncthreads();
    if (tid < 56) {
        int k = tid >> 3, dloc = tid & 7;
        int base = k*32 + dloc*4;
        float a0 = parA[base] + parA[base+1] + parA[base+2] + parA[base+3];
        float a1 = parB[base] + parB[base+1] + parB[base+2] + parB[base+3];
        int d = dc + dloc;
        skvw[((size_t)b*K_ + k)*DB_ + d] = (a0 + skb[k*DB_ + d]) * Rt[d];
        gp1w[((size_t)b*K_ + k)*DB_ + d] = a1;
    } else if (tid < 64) {
        int dloc = tid - 56;
        int base = dloc*4;
        gp2w[(size_t)b*DB_ + dc + dloc] = parC[base] + parC[base+1] + parC[base+2] + parC[base+3];
    }
}

// ---------------- slot_w2 (grid B, 256thr): compat softmax + gate + upd + LN --------------
__global__ __launch_bounds__(256) void slot_w2(
    const float* __restrict__ slots_in, const float* __restrict__ rtp,
    const float* __restrict__ skvw, const float* __restrict__ gp1w,
    const float* __restrict__ gp2w, const float* __restrict__ Wgb,
    const float* __restrict__ lnw, const float* __restrict__ lnb,
    const float* __restrict__ temps,
    float* __restrict__ updw, float* __restrict__ bnw)
{
    int b = blockIdx.x, tid = threadIdx.x;
    __shared__ float sl[K_][DB_], Rt[DB_], upd[K_][DB_];
    __shared__ float compat[K_], swv[K_], mu7[K_], rs7[K_];
    for (int p = tid; p < K_*DB_; p += 256) sl[p>>7][p&127] = slots_in[(size_t)b*K_*DB_ + p];
    if (tid < DB_) {
        float a = 0.f;
        #pragma unroll
        for (int c = 0; c < 8; c++) a += rtp[((size_t)b*8 + c)*DB_ + tid];
        Rt[tid] = a;
    }
    __syncthreads();
    int g = tid >> 5, l32 = tid & 31;
    if (g < K_) {
        float a = 0.f;
        #pragma unroll
        for (int r = 0; r < 4; r++) a += skvw[((size_t)b*K_ + g)*DB_ + l32 + r*32];
        #pragma unroll
        for (int off = 16; off; off >>= 1) a += __shfl_xor(a, off);
        if (l32 == 0) compat[g] = a * SCALE_ * softplusf(temps[g]);
    }
    __syncthreads();
    if (tid == 0) {
        float m = compat[0];
        for (int k = 1; k < K_; k++) m = fmaxf(m, compat[k]);
        float ssum = 0.f;
        for (int k = 0; k < K_; k++) { float e = expf(compat[k]-m); swv[k] = e; ssum += e; }
        for (int k = 0; k < K_; k++) swv[k] /= ssum;
    }
    __syncthreads();
    #pragma unroll
    for (int r = 0; r < 4; r++) {
        int idx = tid + r*256;
        if (idx < K_*DB_) {
            int k = idx >> 7, d = idx & 127;
            float pre = gp1w[(size_t)b*K_*DB_ + idx] + swv[k]*gp2w[(size_t)b*DB_ + d] + Wgb[d];
            float gg = 1.f / (1.f + expf(-pre));
            float u = (1.f - gg)*sl[k][d] + gg*(swv[k]*Rt[d]);
            upd[k][d] = u;
            updw[(size_t)b*K_*DB_ + idx] = u;
        }
    }
    __syncthreads();
    if (g < K_) {
        float s = 0.f, ss = 0.f;
        #pragma unroll
        for (int r = 0; r < 4; r++) { float v = upd[g][l32 + r*32]; s += v; ss += v*v; }
        #pragma unroll
        for (int off = 16; off; off >>= 1) { s += __shfl_xor(s, off); ss += __shfl_xor(ss, off); }
        if (l32 == 0) {
            float mu = s / (float)DB_;
            mu7[g] = mu;
            rs7[g] = rsqrtf(ss/(float)DB_ - mu*mu + 1e-5f);
        }
    }
    __syncthreads();
    #pragma unroll
    for (int r = 0; r < 4; r++) {
        int idx = tid + r*256;
        if (idx < K_*DB_) {
            int k = idx >> 7, d = idx & 127;
            bnw[(size_t)b*K_*DB_ + idx] = (upd[k][d] - mu7[k])*rs7[k]*lnw[d] + lnb[d];
        }
    }
}

// ---------------- slot_qkv (grid (B,12), 256thr): Bn @ Ws{Q,K,V} slices -------------------
__global__ __launch_bounds__(256) void slot_qkv(const float* __restrict__ bnw,
    const float* __restrict__ WsQ, const float* __restrict__ WsK, const float* __restrict__ WsV,
    float* __restrict__ qkvw)
{
    int b = blockIdx.x, m = blockIdx.y >> 2, dc = (blockIdx.y & 3) * 32, tid = threadIdx.x;
    const float* W = (m == 0) ? WsQ : (m == 1) ? WsK : WsV;
    __shared__ float Bn[K_][DB_];
    __shared__ float ws[DB_][32];
    for (int p = tid; p < K_*DB_; p += 256) Bn[p>>7][p&127] = bnw[(size_t)b*K_*DB_ + p];
    #pragma unroll
    for (int i = 0; i < 16; i++) {
        int idx = tid + i*256;
        int row = idx >> 5, col = idx & 31;
        ws[row][col] = W[(size_t)row*DB_ + dc + col];
    }
    __syncthreads();
    if (tid < 224) {
        int k = tid >> 5, dloc = tid & 31;
        float a = 0.f;
        #pragma unroll 8
        for (int e = 0; e < DB_; e++) a += Bn[k][e] * ws[e][dloc];
        qkvw[(((size_t)m*B_ + b)*K_ + k)*DB_ + dc + dloc] = a;
    }
}

// ---------------- slot_fin (grid B, 512thr): sa + ctx + outputs + loss partials -----------
__global__ __launch_bounds__(512) void slot_fin(
    const float* __restrict__ slots_in, const float* __restrict__ updw,
    const float* __restrict__ qkvw, const float* __restrict__ lambda_,
    float* __restrict__ snws, float* __restrict__ out_slots,
    float* __restrict__ lpP, float* __restrict__ lpD)
{
    int b = blockIdx.x, tid = threadIdx.x;
    int lane = tid & 63, wvi = tid >> 6;    // 8 waves
    __shared__ float upd[K_][DB_], qq[K_][DB_], kk2[K_][DB_], vv[K_][DB_], sl[K_][DB_], snsh[K_][DB_];
    __shared__ float sa[K_][K_], nr7[K_], ldv[K_];
    __shared__ float pf[512];
    for (int p = tid; p < K_*DB_; p += 512) {
        int k = p >> 7, d = p & 127;
        upd[k][d] = updw[(size_t)b*K_*DB_ + p];
        qq[k][d]  = qkvw[(((size_t)0*B_ + b)*K_*DB_) + p];
        kk2[k][d] = qkvw[(((size_t)1*B_ + b)*K_*DB_) + p];
        vv[k][d]  = qkvw[(((size_t)2*B_ + b)*K_*DB_) + p];
        sl[k][d]  = slots_in[(size_t)b*K_*DB_ + p];
    }
    __syncthreads();
    if (wvi < K_) {
        int j = lane >> 3, s = lane & 7;
        float acc = 0.f;
        if (j < K_) {
            int e0 = s * 16;
            for (int e = e0; e < e0 + 16; e++) acc += qq[wvi][e] * kk2[j][e];
        }
        #pragma unroll
        for (int off = 4; off; off >>= 1) acc += __shfl_xor(acc, off, 8);
        if (s == 0 && j < K_) sa[wvi][j] = acc * SCALE_;
    }
    __syncthreads();
    if (tid < K_) {
        float m = sa[tid][0];
        for (int j = 1; j < K_; j++) m = fmaxf(m, sa[tid][j]);
        float ssum = 0.f;
        for (int j = 0; j < K_; j++) { float e = expf(sa[tid][j]-m); sa[tid][j] = e; ssum += e; }
        for (int j = 0; j < K_; j++) sa[tid][j] /= ssum;
    }
    __syncthreads();
    float dsq = 0.f;
    #pragma unroll
    for (int r = 0; r < 2; r++) {
        int idx = tid + r*512;
        if (idx < K_*DB_) {
            int k = idx >> 7, d = idx & 127;
            float lam = tanhf(lambda_[d]);
            lam = fminf(fmaxf(lam, -0.5f), 0.5f);
            float c = 0.f;
            #pragma unroll
            for (int j = 0; j < K_; j++) c += sa[k][j] * vv[j][d];
            float sn = upd[k][d] + c * lam;
            snsh[k][d] = sn;
            snws[(size_t)b*K_*DB_ + idx] = sn;
            out_slots[(size_t)b*K_*DB_ + idx] = sn;
            float ddf = sn - sl[k][d];
            dsq += ddf*ddf;
        }
    }
    __syncthreads();
    pf[tid] = dsq;
    if (wvi < K_) {
        float a0 = snsh[wvi][lane], a1 = snsh[wvi][lane + 64];
        float ss = a0*a0 + a1*a1;
        #pragma unroll
        for (int off = 32; off; off >>= 1) ss += __shfl_xor(ss, off);
        if (lane == 0) nr7[wvi] = fmaxf(sqrtf(ss), 1e-12f);
    }
    __syncthreads();
    if (wvi == 0) {
        float s = 0.f;
        #pragma unroll
        for (int q = 0; q < 8; q++) s += pf[lane + q*64];
        #pragma unroll
        for (int off = 32; off; off >>= 1) s += __shfl_xor(s, off);
        if (lane == 0) lpP[b] = s;
    }
    if (wvi >= 1 && wvi <= K_) {
        int q = wvi - 1;
        float accq = 0.f;
        for (int j = 0; j < K_; j++) {
            if (j == q) continue;
            float dt = snsh[q][lane]*snsh[j][lane] + snsh[q][lane+64]*snsh[j][lane+64];
            #pragma unroll
            for (int off = 32; off; off >>= 1) dt += __shfl_xor(dt, off);
            float cs = dt / (nr7[q] * nr7[j]);
            accq += cs*cs;
        }
        if (lane == 0) ldv[q] = accq;
    }
    __syncthreads();
    if (tid == 0) {
        float s = 0.f;
        for (int q = 0; q < K_; q++) s += ldv[q];
        lpD[b] = s;
    }
}

// ---------------- kq & vg (+basis inline, +loss finalize): grid (B, K) ----------------
__global__ __launch_bounds__(256) void kqvg_kernel(
    const float* __restrict__ sn, const float* __restrict__ WKr,
    const float* __restrict__ WQr, const float* __restrict__ WVr,
    const float* __restrict__ rc, const float* __restrict__ w0p,
    const float* __restrict__ lpP, const float* __restrict__ lpD,
    float* __restrict__ kq, float* __restrict__ vg, float* __restrict__ loss_out)
{
    int b = blockIdx.x, k = blockIdx.y, tid = threadIdx.x;
    if (b == 0 && k == 0 && tid == 0) {
        float s = 0.f, s2 = 0.f;
        for (int bb = 0; bb < B_; bb++) { s += lpP[bb]; s2 += lpD[bb]; }
        loss_out[0] = s / (float)(B_*K_*DB_);
        loss_out[1] = s2 / (float)(B_*(K_*K_-K_));
    }
    float P = 0.f, Q = 0.f;
    #pragma unroll
    for (int c = 0; c < 8; c++) {
        P += w0p[((size_t)b*8 + c)*2 + 0];
        Q += w0p[((size_t)b*8 + c)*2 + 1];
    }
    float pm = sqrtf(P), qm2 = sqrtf(Q);
    float tot = pm + qm2 + 1e-6f;
    float b1 = pm / tot, b2 = qm2 / tot;

    __shared__ float sl[DB_], kr[DB_];
    if (tid < DB_) sl[tid] = sn[((size_t)b*K_ + k)*DB_ + tid];
    __syncthreads();
    if (tid < DB_) {
        float a = 0.f;
        for (int e = 0; e < DB_; e++) a += sl[e] * WKr[(size_t)e*DB_ + tid];
        kr[tid] = a;
    }
    __syncthreads();
    #pragma unroll
    for (int rep = 0; rep < 2; rep++) {
        int e = tid + rep*256;
        float a = 0.f;
        const float* wq = WQr + (size_t)e*DB_;
        for (int d = 0; d < DB_; d++) a += kr[d] * wq[d];
        kq[((size_t)b*K_ + k)*D_ + e] = a;
    }
    #pragma unroll
    for (int rep = 0; rep < 2; rep++) {
        int dd = tid + rep*256;
        float a = 0.f;
        for (int e = 0; e < DB_; e++) a += sl[e] * WVr[(size_t)e*D_ + dd];
        float gpre = rc[((size_t)k*3 + 0)*D_ + dd] + b1*rc[((size_t)k*3 + 1)*D_ + dd] + b2*rc[((size_t)k*3 + 2)*D_ + dd];
        float g = tanhf(gpre);
        g = fminf(fmaxf(g, -0.5f), 0.5f);
        vg[((size_t)b*K_ + k)*D_ + dd] = a * g;
    }
}

// ---------------- z: softmax over 7 slots + weighted combine ----------------
__global__ __launch_bounds__(256) void z_kernel(const float* __restrict__ Xr,
                                                const float* __restrict__ kq,
                                                const float* __restrict__ vg,
                                                float* __restrict__ z)
{
    int b = blockIdx.x;
    int t0 = blockIdx.y * 64;
    __shared__ float kqs[K_][D_];
    __shared__ float vgs[K_][D_];
    int tid = threadIdx.x;
    for (int p = tid; p < K_*D_; p += 256) {
        kqs[p>>9][p&511] = kq[(size_t)b*K_*D_ + p];
        vgs[p>>9][p&511] = vg[(size_t)b*K_*D_ + p];
    }
    __syncthreads();
    int lane = tid & 63, w = tid >> 6;
    for (int it = 0; it < 16; it++) {
        int t = t0 + w*16 + it;
        const float* x = Xr + ((size_t)b*T_ + t)*D_;
        float xr[8];
        float s[K_] = {0,0,0,0,0,0,0};
        #pragma unroll
        for (int r = 0; r < 8; r++) {
            int e = lane + r*64;
            xr[r] = x[e];
            #pragma unroll
            for (int k = 0; k < K_; k++) s[k] += xr[r] * kqs[k][e];
        }
        #pragma unroll
        for (int k = 0; k < K_; k++)
            for (int off = 32; off; off >>= 1) s[k] += __shfl_xor(s[k], off);
        float sc[K_];
        float m = NEGINF;
        #pragma unroll
        for (int k = 0; k < K_; k++) { sc[k] = s[k] * SCALE_; m = fmaxf(m, sc[k]); }
        float p[K_], ssum = 0.f;
        #pragma unroll
        for (int k = 0; k < K_; k++) { p[k] = expf(sc[k] - m); ssum += p[k]; }
        float inv = 1.f / ssum;
        float* zp = z + ((size_t)b*T_ + t)*D_;
        #pragma unroll
        for (int r = 0; r < 8; r++) {
            int e = lane + r*64;
            float a = 0.f;
            #pragma unroll
            for (int k = 0; k < K_; k++) a += p[k] * vgs[k][e];
            zp[e] = a * inv;
        }
    }
}

extern "C" void kernel_launch(void* const* d_in, const int* in_sizes, int n_in,
                              void* d_out, int out_size, void* d_ws, size_t ws_size,
                              hipStream_t stream)
{
    const float* X_write = (const float*)d_in[0];
    const float* X_read  = (const float*)d_in[1];
    const float* slots   = (const float*)d_in[2];
    const float* W0      = (const float*)d_in[3];
    const float* lnw_w   = (const float*)d_in[4];
    const float* lnw_b   = (const float*)d_in[5];
    const float* W_V     = (const float*)d_in[6];
    const float* W_K_slot= (const float*)d_in[7];
    const float* skb     = (const float*)d_in[8];
    const float* Wg      = (const float*)d_in[9];
    const float* Wgb     = (const float*)d_in[10];
    const float* lns_w   = (const float*)d_in[11];
    const float* lns_b   = (const float*)d_in[12];
    const float* WsQ     = (const float*)d_in[13];
    const float* WsK     = (const float*)d_in[14];
    const float* WsV     = (const float*)d_in[15];
    const float* lambda_ = (const float*)d_in[16];
    const float* WQr     = (const float*)d_in[17];
    const float* WKr     = (const float*)d_in[18];
    const float* WVr     = (const float*)d_in[19];
    const float* rc      = (const float*)d_in[20];
    const float* temps   = (const float*)d_in[21];

    const size_t NXD = (size_t)B_*T_*D_;           // 16777216
    unsigned short* Xh  = (unsigned short*)d_ws;
    unsigned short* Xl  = Xh + NXD;
    float* Cf           = (float*)(Xl + NXD);      // f32 XW0, 64MB
    unsigned short* W0h = (unsigned short*)(Cf + NXD);
    unsigned short* W0l = W0h + (size_t)D_*D_;
    float* fscr  = (float*)(W0l + (size_t)D_*D_);
    float* qpart = fscr;                           // B*32*D = 262144
    float* w0p   = qpart + (size_t)B_*32*D_;       // 256
    float* snws  = w0p + 256;                      // 14336
    float* kq    = snws + (size_t)B_*K_*DB_;       // 57344
    float* vg    = kq + (size_t)B_*K_*D_;          // 57344
    float* cv    = vg + (size_t)B_*K_*D_;          // B*4096 = 65536
    int*   ci    = (int*)(cv + (size_t)B_*4096);   // 65536
    float* lpP   = (float*)(ci + (size_t)B_*4096); // 16
    float* lpD   = lpP + 16;                       // 16
    float* yws   = lpD + 16;                       // B*D = 8192
    float* rtp   = yws + (size_t)B_*D_;            // B*8*128 = 16384
    float* skvw  = rtp + (size_t)B_*8*DB_;         // B*896 = 14336
    float* gp1w  = skvw + (size_t)B_*K_*DB_;       // 14336
    float* gp2w  = gp1w + (size_t)B_*K_*DB_;       // B*128 = 2048
    float* updw  = gp2w + (size_t)B_*DB_;          // 14336
    float* bnw   = updw + (size_t)B_*K_*DB_;       // 14336
    float* qkvw  = bnw + (size_t)B_*K_*DB_;        // 3*B*896 = 43008

    float* z_out     = (float*)d_out;
    float* slots_out = z_out + NXD;
    float* loss_out  = slots_out + (size_t)B_*K_*DB_;
    float* sal       = z_out;    // scratch inside z region; consumed before z_kernel writes

    prep_kernel<<<dim3(4096 + 256 + 512), dim3(256), 0, stream>>>(
        X_write, lnw_w, lnw_b, Xh, Xl, W0, W0h, W0l, X_read, qpart);
    gemm_xw0_mfma<<<dim3(B_*T_/128, D_/128), dim3(256), 0, stream>>>(Xh, Xl, W0h, W0l, Cf);
    sal_mfma<<<dim3(B_, T_/64), dim3(256), 0, stream>>>(Xh, Xl, Cf, sal);
    topk_stage1<<<dim3(B_, 72), dim3(256), 0, stream>>>(sal, cv, ci, qpart, W0, w0p);
    slot_head<<<dim3(B_), dim3(512), 0, stream>>>(Xh, Xl, cv, ci, yws);
    slot_rt<<<dim3(B_, 8), dim3(256), 0, stream>>>(yws, W_V, rtp);
    slot_w1<<<dim3(B_, 16), dim3(256), 0, stream>>>(slots, rtp, W_K_slot, skb, Wg,
        skvw, gp1w, gp2w);
    slot_w2<<<dim3(B_), dim3(256), 0, stream>>>(slots, rtp, skvw, gp1w, gp2w, Wgb,
        lns_w, lns_b, temps, updw, bnw);
    slot_qkv<<<dim3(B_, 12), dim3(256), 0, stream>>>(bnw, WsQ, WsK, WsV, qkvw);
    slot_fin<<<dim3(B_), dim3(512), 0, stream>>>(slots, updw, qkvw, lambda_,
        snws, slots_out, lpP, lpD);
    kqvg_kernel<<<dim3(B_, K_), dim3(256), 0, stream>>>(snws, WKr, WQr, WVr, rc, w0p,
        lpP, lpD, kq, vg, loss_out);
    z_kernel<<<dim3(B_, T_/64), dim3(256), 0, stream>>>(X_read, kq, vg, z_out);
}